// Round 15
// baseline (342.948 us; speedup 1.0000x reference)
//
#include <hip/hip_runtime.h>
#include <hip/hip_bf16.h>
#include <hip/hip_fp16.h>
#include <math.h>

#define NNODES 50000
#define NEDGES 800000
#define FIN 128
#define FH 256
#define NG 64
#define NC 64
#define SCAN_NB ((NNODES + 255) / 256)
#define NP 50176              // K padded to 196*256
#define QSK 196               // split-K blocks for qsum (NP/256)

typedef unsigned short bhalf;
typedef __attribute__((ext_vector_type(8))) short bf16x8;
typedef __attribute__((ext_vector_type(4))) float f32x4;
typedef __attribute__((ext_vector_type(4))) unsigned short u16x4;

__device__ inline bhalf f2bf_rn(float f) {
    unsigned int u = __float_as_uint(f);
    u += 0x7FFFu + ((u >> 16) & 1u);      // round-to-nearest-even
    return (bhalf)(u >> 16);
}
__device__ inline float bf2f(bhalf h) { return __uint_as_float(((unsigned int)h) << 16); }
__device__ inline float2 bfpair(unsigned int u) {   // [lo16, hi16] -> two floats
    return make_float2(__uint_as_float(u << 16), __uint_as_float(u & 0xFFFF0000u));
}
__device__ inline float edec_norm(unsigned int ed) {  // low 16 bits = f16 norm
    return __half2float(__ushort_as_half((unsigned short)(ed & 0xFFFFu)));
}

// ---------------- degree ----------------

__global__ void degree_kernel(const int* __restrict__ dst, int* __restrict__ degi, int E) {
    int e = blockIdx.x * blockDim.x + threadIdx.x;
    if (e < E) atomicAdd(&degi[dst[e]], 1);
}

// ---------------- 2-level exclusive scan over degi -> row_start (+ fused dinv) ----------------

__global__ __launch_bounds__(256)
void scan_block_kernel(const int* __restrict__ degi, int* __restrict__ local_ex,
                       int* __restrict__ partial, float* __restrict__ dinv, int Nn) {
    __shared__ int s[256];
    int i = blockIdx.x * 256 + threadIdx.x;
    int v = (i < Nn) ? degi[i] : 0;
    s[threadIdx.x] = v;
    __syncthreads();
#pragma unroll
    for (int off = 1; off < 256; off <<= 1) {
        int t = (threadIdx.x >= off) ? s[threadIdx.x - off] : 0;
        __syncthreads();
        s[threadIdx.x] += t;
        __syncthreads();
    }
    if (i < Nn) {
        local_ex[i] = s[threadIdx.x] - v;
        dinv[i] = rsqrtf((float)v + 1.0f);
    }
    if (threadIdx.x == 255) partial[blockIdx.x] = s[255];
}

__global__ __launch_bounds__(256)
void scan_partial_kernel(int* __restrict__ partial, int nb) {
    __shared__ int s[256];
    int v = (threadIdx.x < nb) ? partial[threadIdx.x] : 0;
    s[threadIdx.x] = v;
    __syncthreads();
#pragma unroll
    for (int off = 1; off < 256; off <<= 1) {
        int t = (threadIdx.x >= off) ? s[threadIdx.x - off] : 0;
        __syncthreads();
        s[threadIdx.x] += t;
        __syncthreads();
    }
    if (threadIdx.x < nb) partial[threadIdx.x] = s[threadIdx.x] - v;
}

__global__ void add_offsets_kernel(int* __restrict__ row_start, const int* __restrict__ local_ex,
                                   const int* __restrict__ partial, int Nn) {
    int i = blockIdx.x * 256 + threadIdx.x;
    if (i < Nn) row_start[i] = local_ex[i] + partial[blockIdx.x];
}

// ---------------- edge placement: CSR by dst, packed (src:u16 | f16 norm) ----------------

__global__ void edge_place_kernel(const int* __restrict__ src, const int* __restrict__ dst,
                                  const int* __restrict__ row_start, int* __restrict__ cursor,
                                  const float* __restrict__ dinv,
                                  unsigned int* __restrict__ edata, int E) {
    int e = blockIdx.x * blockDim.x + threadIdx.x;
    if (e >= E) return;
    int s = src[e], d = dst[e];
    int pos = row_start[d] + atomicAdd(&cursor[d], 1);
    float nm = dinv[s] * dinv[d];
    unsigned short hb = __half_as_ushort(__float2half(nm));
    edata[pos] = ((unsigned int)s << 16) | (unsigned int)hb;
}

// ---------------- pooling-weight build: 8-lane subgroup per dst node, wt[g][src] += norm ----------------

__global__ void wbuild_kernel(const unsigned int* __restrict__ edata,
                              const int* __restrict__ row_start, const int* __restrict__ degi,
                              const int* __restrict__ batch, const float* __restrict__ dinv,
                              float* __restrict__ wt, int Nn) {
    int t = blockIdx.x * blockDim.x + threadIdx.x;
    int n = t >> 3;                    // 8 lanes per node
    int l = t & 7;
    if (n >= Nn) return;
    float* row = &wt[(size_t)batch[n] * NP];
    int st = row_start[n], cnt = degi[n];
    for (int j = l; j < cnt; j += 8) {
        unsigned int ed = edata[st + j];
        atomicAdd(&row[ed >> 16], edec_norm(ed));
    }
    if (l == 0) {
        float sn = dinv[n];
        atomicAdd(&row[n], sn * sn);
    }
}

// ---------------- wt f32 -> bf16 hi/lo split (error-free to ~2^-16) ----------------

__global__ void cvt_wt_kernel(const float* __restrict__ wt, bhalf* __restrict__ wthi,
                              bhalf* __restrict__ wtlo, int total4) {
    int i = blockIdx.x * blockDim.x + threadIdx.x;
    if (i >= total4) return;
    float4 v = *reinterpret_cast<const float4*>(&wt[i * 4]);
    u16x4 hi = {f2bf_rn(v.x), f2bf_rn(v.y), f2bf_rn(v.z), f2bf_rn(v.w)};
    u16x4 lo = {f2bf_rn(v.x - bf2f(hi.x)), f2bf_rn(v.y - bf2f(hi.y)),
                f2bf_rn(v.z - bf2f(hi.z)), f2bf_rn(v.w - bf2f(hi.w))};
    *reinterpret_cast<u16x4*>(&wthi[i * 4]) = hi;
    *reinterpret_cast<u16x4*>(&wtlo[i * 4]) = lo;
}

// ---------------- x -> bf16 copy ----------------

__global__ void split_x_kernel(const float* __restrict__ x, bhalf* __restrict__ xb, int total4) {
    int i = blockIdx.x * blockDim.x + threadIdx.x;
    if (i >= total4) return;
    float4 v = *reinterpret_cast<const float4*>(&x[i * 4]);
    u16x4 o = {f2bf_rn(v.x), f2bf_rn(v.y), f2bf_rn(v.z), f2bf_rn(v.w)};
    *reinterpret_cast<u16x4*>(&xb[i * 4]) = o;
}

// ---------------- weight round+transpose: W1[K][256] f32 -> Wt [256][K] bf16 ----------------

__global__ void split_w_kernel(const float* __restrict__ W, bhalf* __restrict__ Wt, int K) {
    int idx = blockIdx.x * 256 + threadIdx.x;
    if (idx >= K * 256) return;
    int k = idx >> 8, n = idx & 255;
    Wt[n * K + k] = f2bf_rn(W[idx]);
}

// ---------------- CSR gather, 128 bf16 feats: z[n] = bf16(sum + x[n]*sn), unroll-4 ----------------

__global__ __launch_bounds__(256)
void gather128_kernel(const bhalf* __restrict__ xb, const unsigned int* __restrict__ edata,
                      const int* __restrict__ row_start, const int* __restrict__ degi,
                      const float* __restrict__ dinv, bhalf* __restrict__ z, int Nn) {
    int node = blockIdx.x * 4 + (threadIdx.x >> 6);
    if (node >= Nn) return;
    int lane = threadIdx.x & 63;
    int st = row_start[node];
    int cnt = degi[node];
    float ax = 0.0f, ay = 0.0f;
    int j = 0;
    for (; j + 3 < cnt; j += 4) {
        unsigned int e0 = edata[st + j],     e1 = edata[st + j + 1];
        unsigned int e2 = edata[st + j + 2], e3 = edata[st + j + 3];
        float2 v0 = bfpair(*reinterpret_cast<const unsigned int*>(&xb[(size_t)(e0 >> 16) * FIN + lane * 2]));
        float2 v1 = bfpair(*reinterpret_cast<const unsigned int*>(&xb[(size_t)(e1 >> 16) * FIN + lane * 2]));
        float2 v2 = bfpair(*reinterpret_cast<const unsigned int*>(&xb[(size_t)(e2 >> 16) * FIN + lane * 2]));
        float2 v3 = bfpair(*reinterpret_cast<const unsigned int*>(&xb[(size_t)(e3 >> 16) * FIN + lane * 2]));
        float n0 = edec_norm(e0), n1 = edec_norm(e1), n2 = edec_norm(e2), n3 = edec_norm(e3);
        ax += v0.x * n0 + v1.x * n1 + v2.x * n2 + v3.x * n3;
        ay += v0.y * n0 + v1.y * n1 + v2.y * n2 + v3.y * n3;
    }
    for (; j < cnt; j++) {
        unsigned int e0 = edata[st + j];
        float2 v0 = bfpair(*reinterpret_cast<const unsigned int*>(&xb[(size_t)(e0 >> 16) * FIN + lane * 2]));
        float n0 = edec_norm(e0);
        ax += v0.x * n0; ay += v0.y * n0;
    }
    float sn = dinv[node];
    sn *= sn;
    float2 xv = bfpair(*reinterpret_cast<const unsigned int*>(&xb[(size_t)node * FIN + lane * 2]));
    ushort2 o = {f2bf_rn(ax + xv.x * sn), f2bf_rn(ay + xv.y * sn)};
    *reinterpret_cast<ushort2*>(&z[(size_t)node * FIN + lane * 2]) = o;
}

// ---------------- MFMA bf16 GEMM: h1t[col][row] = bf16(gelu(A@Bt^T + bias)) ----------------
// Output TRANSPOSED [256][NP]: acc r=0..3 are 4 consecutive rows -> packed 8 B stores.

__global__ __launch_bounds__(256)
void gemm_mfma_kernel(const bhalf* __restrict__ A, const bhalf* __restrict__ Bt,
                      const float* __restrict__ bias, bhalf* __restrict__ h1t,
                      int M, int Kp) {
    __shared__ bhalf As[128 * 72];   // rows x (64+8 pad): 144 B row stride (16B-aligned)
    __shared__ bhalf Bs[128 * 72];
    const int tid  = threadIdx.x;
    const int lane = tid & 63;
    const int wave = tid >> 6;
    const int quad = lane >> 4;
    const int l15  = lane & 15;
    const int wm = (wave & 1) * 64;
    const int wn = (wave >> 1) * 64;
    const int bm = blockIdx.x * 128;
    const int bn = blockIdx.y * 128;

    f32x4 acc[4][4] = {};

    for (int k0 = 0; k0 < Kp; k0 += 64) {
#pragma unroll
        for (int i = 0; i < 4; i++) {
            int chunk = tid + i * 256;           // 1024 chunks of 8 bf16
            int r = chunk >> 3, c16 = chunk & 7;
            int gm = bm + r;
            float4 va = make_float4(0.f, 0.f, 0.f, 0.f);
            if (gm < M) va = *reinterpret_cast<const float4*>(&A[(size_t)gm * Kp + k0 + c16 * 8]);
            *reinterpret_cast<float4*>(&As[r * 72 + c16 * 8]) = va;
            float4 vb = *reinterpret_cast<const float4*>(&Bt[(size_t)(bn + r) * Kp + k0 + c16 * 8]);
            *reinterpret_cast<float4*>(&Bs[r * 72 + c16 * 8]) = vb;
        }
        __syncthreads();
#pragma unroll
        for (int kk = 0; kk < 64; kk += 32) {
            bf16x8 af[4], bfr[4];
#pragma unroll
            for (int mi = 0; mi < 4; mi++)
                af[mi] = *reinterpret_cast<const bf16x8*>(&As[(wm + mi * 16 + l15) * 72 + kk + quad * 8]);
#pragma unroll
            for (int ni = 0; ni < 4; ni++)
                bfr[ni] = *reinterpret_cast<const bf16x8*>(&Bs[(wn + ni * 16 + l15) * 72 + kk + quad * 8]);
#pragma unroll
            for (int mi = 0; mi < 4; mi++)
#pragma unroll
                for (int ni = 0; ni < 4; ni++)
                    acc[mi][ni] = __builtin_amdgcn_mfma_f32_16x16x32_bf16(af[mi], bfr[ni], acc[mi][ni], 0, 0, 0);
        }
        __syncthreads();
    }

    // epilogue: C/D col = lane&15, row = quad*4 + r. Write transposed: h1t[col][row0..row0+3].
#pragma unroll
    for (int mi = 0; mi < 4; mi++) {
        int row0 = bm + wm + mi * 16 + quad * 4;   // rows row0..row0+3 < NP always
#pragma unroll
        for (int ni = 0; ni < 4; ni++) {
            int col = bn + wn + ni * 16 + l15;
            float bv = bias[col];
            u16x4 o;
#pragma unroll
            for (int r = 0; r < 4; r++) {
                float v = acc[mi][ni][r] + bv;
                v = 0.5f * v * (1.0f + erff(v * 0.70710678118654752f));
                o[r] = f2bf_rn(v);
            }
            *reinterpret_cast<u16x4*>(&h1t[(size_t)col * NP + row0]) = o;
        }
    }
}

// ---------------- qsum MFMA: qT[256][64] partials = h1t @ {wthi,wtlo}^T over K chunk ----------------
// Both operands K(=node)-contiguous; garbage h1t tail killed by zero wt tail.

__global__ __launch_bounds__(256)
void qsum_mfma_kernel(const bhalf* __restrict__ h1t, const bhalf* __restrict__ wthi,
                      const bhalf* __restrict__ wtlo, float* __restrict__ qpart) {
    const int tid  = threadIdx.x;
    const int lane = tid & 63;
    const int wave = tid >> 6;
    const int quad = lane >> 4;
    const int l15  = lane & 15;
    const int m0 = wave * 64;
    const size_t kbase = (size_t)blockIdx.x * 256 + quad * 8;
    f32x4 acc[4][4] = {};
#pragma unroll
    for (int ks = 0; ks < 8; ks++) {
        size_t k0 = kbase + ks * 32;
        bf16x8 af[4], bh[4], bl[4];
#pragma unroll
        for (int mi = 0; mi < 4; mi++)
            af[mi] = *reinterpret_cast<const bf16x8*>(&h1t[(size_t)(m0 + mi * 16 + l15) * NP + k0]);
#pragma unroll
        for (int ni = 0; ni < 4; ni++) {
            bh[ni] = *reinterpret_cast<const bf16x8*>(&wthi[(size_t)(ni * 16 + l15) * NP + k0]);
            bl[ni] = *reinterpret_cast<const bf16x8*>(&wtlo[(size_t)(ni * 16 + l15) * NP + k0]);
        }
#pragma unroll
        for (int mi = 0; mi < 4; mi++)
#pragma unroll
            for (int ni = 0; ni < 4; ni++) {
                acc[mi][ni] = __builtin_amdgcn_mfma_f32_16x16x32_bf16(af[mi], bh[ni], acc[mi][ni], 0, 0, 0);
                acc[mi][ni] = __builtin_amdgcn_mfma_f32_16x16x32_bf16(af[mi], bl[ni], acc[mi][ni], 0, 0, 0);
            }
    }
    float* qp = &qpart[(size_t)blockIdx.x * FH * NG];
#pragma unroll
    for (int mi = 0; mi < 4; mi++)
#pragma unroll
        for (int r = 0; r < 4; r++) {
            int row = m0 + mi * 16 + quad * 4 + r;   // c-dim 0..255
#pragma unroll
            for (int ni = 0; ni < 4; ni++) {
                int col = ni * 16 + l15;             // g-dim 0..63
                qp[row * NG + col] = acc[mi][ni][r];
            }
        }
}

__global__ __launch_bounds__(256)
void qreduce_kernel(const float* __restrict__ qpart, float* __restrict__ q) {
    int idx = blockIdx.x * 256 + threadIdx.x;   // 16384 cells of qT [c][g]
    float s = 0.0f;
    for (int b = 0; b < QSK; b++)
        s += qpart[(size_t)b * FH * NG + idx];
    q[idx] = s;
}

// ---------------- pooled = (qT^T @ W2) / cnt_g + b2 ----------------

__global__ __launch_bounds__(256)
void p2_kernel(const float* __restrict__ q, const float* __restrict__ W2,
               const float* __restrict__ b2, const int* __restrict__ batch,
               float* __restrict__ pooled) {
    int g = blockIdx.x;
    int c = threadIdx.x;
    int lo = 0, hi = NNODES;
    while (lo < hi) { int m = (lo + hi) >> 1; if (batch[m] < g) lo = m + 1; else hi = m; }
    int a = lo;
    lo = 0; hi = NNODES;
    while (lo < hi) { int m = (lo + hi) >> 1; if (batch[m] < g + 1) lo = m + 1; else hi = m; }
    float inv = 1.0f / fmaxf((float)(lo - a), 1.0f);
    float acc = 0.0f;
    for (int k = 0; k < FH; k++)
        acc += q[k * NG + g] * W2[k * FH + c];   // qT[k][g]
    pooled[g * FH + c] = acc * inv + b2[c];
}

// ---------------- FC head ----------------

__global__ __launch_bounds__(64)
void fc_kernel(const float* __restrict__ pooled, const float* __restrict__ Wfc,
               const float* __restrict__ bfc, float* __restrict__ out) {
    int g = blockIdx.x;
    int c2 = threadIdx.x;
    float acc = 0.0f;
    for (int c = 0; c < FH; c++)
        acc += pooled[g * FH + c] * Wfc[c * NC + c2];
    out[g * NC + c2] = acc + bfc[c2];
}

// ---------------- launch ----------------

extern "C" void kernel_launch(void* const* d_in, const int* in_sizes, int n_in,
                              void* d_out, int out_size, void* d_ws, size_t ws_size,
                              hipStream_t stream) {
    const float* x    = (const float*)d_in[0];
    const int*   ei   = (const int*)d_in[1];
    const int*   batch= (const int*)d_in[2];
    const float* W1   = (const float*)d_in[3];
    const float* b1   = (const float*)d_in[4];
    const float* W2   = (const float*)d_in[5];
    const float* b2   = (const float*)d_in[6];
    const float* Wfc  = (const float*)d_in[7];
    const float* bfc  = (const float*)d_in[8];
    float* out = (float*)d_out;

    const int* src = ei;
    const int* dst = ei + NEDGES;

    // workspace (~94 MB):
    bhalf* xb        = (bhalf*)d_ws;                       // [N,128] bf16 (12.8 MB)
    bhalf* zb        = xb + (size_t)NNODES * FIN;          // [N,128] bf16 (12.8 MB)
    bhalf* h1t       = zb + (size_t)NNODES * FIN;          // [256,NP] bf16 (25.7 MB)
    unsigned int* edata = (unsigned int*)(h1t + (size_t)FH * NP);  // [E] packed (3.2 MB)
    int*   row_start = (int*)(edata + NEDGES);             // [N]
    int*   local_ex  = row_start + NNODES;                 // [N]
    int*   partial   = local_ex + NNODES;                  // [256]
    float* dinv      = (float*)(partial + 256);            // [N]
    bhalf* w1t       = (bhalf*)(dinv + NNODES);            // [256,128] bf16
    bhalf* wthi      = w1t + 256 * FIN;                    // [64,NP] bf16 (6.4 MB)
    bhalf* wtlo      = wthi + (size_t)NG * NP;             // [64,NP] bf16 (6.4 MB)
    float* qpart     = (float*)(wtlo + (size_t)NG * NP);   // [QSK,256,64] f32 (12.85 MB)
    float* q         = qpart + (size_t)QSK * FH * NG;      // [256,64] qT
    float* pooled    = q + FH * NG;                        // [64,256]
    // ---- contiguous zeroed region ----
    int*   degi      = (int*)(pooled + NG * FH);           // [N]
    int*   cursor    = degi + NNODES;                      // [N]
    float* wt        = (float*)(cursor + NNODES);          // [64,NP] f32 (12.85 MB, zero tail!)
    size_t zero_bytes = (size_t)(2 * NNODES) * 4 + (size_t)NG * NP * 4;

    (void)hipMemsetAsync(degi, 0, zero_bytes, stream);

    // ---- CSR build + norms ----
    degree_kernel<<<(NEDGES + 255) / 256, 256, 0, stream>>>(dst, degi, NEDGES);
    scan_block_kernel<<<SCAN_NB, 256, 0, stream>>>(degi, local_ex, partial, dinv, NNODES);
    scan_partial_kernel<<<1, 256, 0, stream>>>(partial, SCAN_NB);
    add_offsets_kernel<<<SCAN_NB, 256, 0, stream>>>(row_start, local_ex, partial, NNODES);
    edge_place_kernel<<<(NEDGES + 255) / 256, 256, 0, stream>>>(src, dst, row_start, cursor,
                                                                dinv, edata, NEDGES);
    wbuild_kernel<<<(NNODES * 8 + 255) / 256, 256, 0, stream>>>(edata, row_start, degi,
                                                                batch, dinv, wt, NNODES);
    cvt_wt_kernel<<<(NG * NP / 4 + 255) / 256, 256, 0, stream>>>(wt, wthi, wtlo, NG * NP / 4);

    // ---- bf16 conversions ----
    split_x_kernel<<<(NNODES * FIN / 4 + 255) / 256, 256, 0, stream>>>(x, xb, NNODES * FIN / 4);
    split_w_kernel<<<(FIN * 256 + 255) / 256, 256, 0, stream>>>(W1, w1t, FIN);

    int gather_blocks = (NNODES + 3) / 4;
    dim3 mgrid((NNODES + 127) / 128, 2);

    // conv1 (aggregate-first): z = bf16(Ahat*x) ; h1t = bf16(gelu(z@W1 + b1))^T
    gather128_kernel<<<gather_blocks, 256, 0, stream>>>(xb, edata, row_start, degi,
                                                        dinv, zb, NNODES);
    gemm_mfma_kernel<<<mgrid, 256, 0, stream>>>(zb, w1t, b1, h1t, NNODES, FIN);

    // conv2 + pool collapsed via MFMA: qT = h1t @ wt^T ; pooled = (q@W2)/cnt + b2 ; out = @Wfc
    qsum_mfma_kernel<<<QSK, 256, 0, stream>>>(h1t, wthi, wtlo, qpart);
    qreduce_kernel<<<FH * NG / 256, 256, 0, stream>>>(qpart, q);
    p2_kernel<<<NG, FH, 0, stream>>>(q, W2, b2, batch, pooled);
    fc_kernel<<<NG, NC, 0, stream>>>(pooled, Wfc, bfc, out);
}

// Round 16
// 333.863 us; speedup vs baseline: 1.0272x; 1.0272x over previous
//
#include <hip/hip_runtime.h>
#include <hip/hip_bf16.h>
#include <hip/hip_fp16.h>
#include <math.h>

#define NNODES 50000
#define NEDGES 800000
#define FIN 128
#define FH 256
#define NG 64
#define NC 64
#define SCAN_NB ((NNODES + 255) / 256)
#define NP 50176              // K padded to 196*256
#define QSK 196               // split-K blocks for qsum (NP/256)

typedef unsigned short bhalf;
typedef __attribute__((ext_vector_type(8))) short bf16x8;
typedef __attribute__((ext_vector_type(4))) float f32x4;
typedef __attribute__((ext_vector_type(4))) unsigned short u16x4;

__device__ inline bhalf f2bf_rn(float f) {
    unsigned int u = __float_as_uint(f);
    u += 0x7FFFu + ((u >> 16) & 1u);      // round-to-nearest-even
    return (bhalf)(u >> 16);
}
__device__ inline float bf2f(bhalf h) { return __uint_as_float(((unsigned int)h) << 16); }
__device__ inline float2 bfpair(unsigned int u) {   // [lo16, hi16] -> two floats
    return make_float2(__uint_as_float(u << 16), __uint_as_float(u & 0xFFFF0000u));
}
__device__ inline float edec_norm(unsigned int ed) {  // low 16 bits = f16 norm
    return __half2float(__ushort_as_half((unsigned short)(ed & 0xFFFFu)));
}

// ---------------- degree ----------------

__global__ void degree_kernel(const int* __restrict__ dst, int* __restrict__ degi, int E) {
    int e = blockIdx.x * blockDim.x + threadIdx.x;
    if (e < E) atomicAdd(&degi[dst[e]], 1);
}

// ---------------- 2-level exclusive scan over degi -> row_start (+ fused dinv) ----------------

__global__ __launch_bounds__(256)
void scan_block_kernel(const int* __restrict__ degi, int* __restrict__ local_ex,
                       int* __restrict__ partial, float* __restrict__ dinv, int Nn) {
    __shared__ int s[256];
    int i = blockIdx.x * 256 + threadIdx.x;
    int v = (i < Nn) ? degi[i] : 0;
    s[threadIdx.x] = v;
    __syncthreads();
#pragma unroll
    for (int off = 1; off < 256; off <<= 1) {
        int t = (threadIdx.x >= off) ? s[threadIdx.x - off] : 0;
        __syncthreads();
        s[threadIdx.x] += t;
        __syncthreads();
    }
    if (i < Nn) {
        local_ex[i] = s[threadIdx.x] - v;
        dinv[i] = rsqrtf((float)v + 1.0f);
    }
    if (threadIdx.x == 255) partial[blockIdx.x] = s[255];
}

__global__ __launch_bounds__(256)
void scan_partial_kernel(int* __restrict__ partial, int nb) {
    __shared__ int s[256];
    int v = (threadIdx.x < nb) ? partial[threadIdx.x] : 0;
    s[threadIdx.x] = v;
    __syncthreads();
#pragma unroll
    for (int off = 1; off < 256; off <<= 1) {
        int t = (threadIdx.x >= off) ? s[threadIdx.x - off] : 0;
        __syncthreads();
        s[threadIdx.x] += t;
        __syncthreads();
    }
    if (threadIdx.x < nb) partial[threadIdx.x] = s[threadIdx.x] - v;
}

// ---------------- add offsets + wt self-loop term ----------------

__global__ void add_offsets_kernel(int* __restrict__ row_start, const int* __restrict__ local_ex,
                                   const int* __restrict__ partial, const int* __restrict__ batch,
                                   const float* __restrict__ dinv, float* __restrict__ wt, int Nn) {
    int i = blockIdx.x * 256 + threadIdx.x;
    if (i < Nn) {
        row_start[i] = local_ex[i] + partial[blockIdx.x];
        float sn = dinv[i];
        atomicAdd(&wt[(size_t)batch[i] * NP + i], sn * sn);
    }
}

// ---------------- edge placement + pooling-weight build (merged single pass) ----------------
// CSR by dst, packed (src:u16 | f16 norm); also wt[batch[d]][s] += norm.

__global__ void edge_place_kernel(const int* __restrict__ src, const int* __restrict__ dst,
                                  const int* __restrict__ row_start, int* __restrict__ cursor,
                                  const float* __restrict__ dinv, const int* __restrict__ batch,
                                  unsigned int* __restrict__ edata, float* __restrict__ wt, int E) {
    int e = blockIdx.x * blockDim.x + threadIdx.x;
    if (e >= E) return;
    int s = src[e], d = dst[e];
    int pos = row_start[d] + atomicAdd(&cursor[d], 1);
    float nm = dinv[s] * dinv[d];
    unsigned short hb = __half_as_ushort(__float2half(nm));
    edata[pos] = ((unsigned int)s << 16) | (unsigned int)hb;
    atomicAdd(&wt[(size_t)batch[d] * NP + s], nm);
}

// ---------------- wt f32 -> bf16 hi/lo split (error-free to ~2^-16) ----------------

__global__ void cvt_wt_kernel(const float* __restrict__ wt, bhalf* __restrict__ wthi,
                              bhalf* __restrict__ wtlo, int total4) {
    int i = blockIdx.x * blockDim.x + threadIdx.x;
    if (i >= total4) return;
    float4 v = *reinterpret_cast<const float4*>(&wt[i * 4]);
    u16x4 hi = {f2bf_rn(v.x), f2bf_rn(v.y), f2bf_rn(v.z), f2bf_rn(v.w)};
    u16x4 lo = {f2bf_rn(v.x - bf2f(hi.x)), f2bf_rn(v.y - bf2f(hi.y)),
                f2bf_rn(v.z - bf2f(hi.z)), f2bf_rn(v.w - bf2f(hi.w))};
    *reinterpret_cast<u16x4*>(&wthi[i * 4]) = hi;
    *reinterpret_cast<u16x4*>(&wtlo[i * 4]) = lo;
}

// ---------------- x -> bf16 copy ----------------

__global__ void split_x_kernel(const float* __restrict__ x, bhalf* __restrict__ xb, int total4) {
    int i = blockIdx.x * blockDim.x + threadIdx.x;
    if (i >= total4) return;
    float4 v = *reinterpret_cast<const float4*>(&x[i * 4]);
    u16x4 o = {f2bf_rn(v.x), f2bf_rn(v.y), f2bf_rn(v.z), f2bf_rn(v.w)};
    *reinterpret_cast<u16x4*>(&xb[i * 4]) = o;
}

// ---------------- weight round+transpose: W1[K][256] f32 -> Wt [256][K] bf16 ----------------

__global__ void split_w_kernel(const float* __restrict__ W, bhalf* __restrict__ Wt, int K) {
    int idx = blockIdx.x * 256 + threadIdx.x;
    if (idx >= K * 256) return;
    int k = idx >> 8, n = idx & 255;
    Wt[n * K + k] = f2bf_rn(W[idx]);
}

// ---------------- CSR gather, 128 bf16 feats: z[n] = bf16(sum + x[n]*sn), unroll-4 ----------------

__global__ __launch_bounds__(256)
void gather128_kernel(const bhalf* __restrict__ xb, const unsigned int* __restrict__ edata,
                      const int* __restrict__ row_start, const int* __restrict__ degi,
                      const float* __restrict__ dinv, bhalf* __restrict__ z, int Nn) {
    int node = blockIdx.x * 4 + (threadIdx.x >> 6);
    if (node >= Nn) return;
    int lane = threadIdx.x & 63;
    int st = row_start[node];
    int cnt = degi[node];
    float ax = 0.0f, ay = 0.0f;
    int j = 0;
    for (; j + 3 < cnt; j += 4) {
        unsigned int e0 = edata[st + j],     e1 = edata[st + j + 1];
        unsigned int e2 = edata[st + j + 2], e3 = edata[st + j + 3];
        float2 v0 = bfpair(*reinterpret_cast<const unsigned int*>(&xb[(size_t)(e0 >> 16) * FIN + lane * 2]));
        float2 v1 = bfpair(*reinterpret_cast<const unsigned int*>(&xb[(size_t)(e1 >> 16) * FIN + lane * 2]));
        float2 v2 = bfpair(*reinterpret_cast<const unsigned int*>(&xb[(size_t)(e2 >> 16) * FIN + lane * 2]));
        float2 v3 = bfpair(*reinterpret_cast<const unsigned int*>(&xb[(size_t)(e3 >> 16) * FIN + lane * 2]));
        float n0 = edec_norm(e0), n1 = edec_norm(e1), n2 = edec_norm(e2), n3 = edec_norm(e3);
        ax += v0.x * n0 + v1.x * n1 + v2.x * n2 + v3.x * n3;
        ay += v0.y * n0 + v1.y * n1 + v2.y * n2 + v3.y * n3;
    }
    for (; j < cnt; j++) {
        unsigned int e0 = edata[st + j];
        float2 v0 = bfpair(*reinterpret_cast<const unsigned int*>(&xb[(size_t)(e0 >> 16) * FIN + lane * 2]));
        float n0 = edec_norm(e0);
        ax += v0.x * n0; ay += v0.y * n0;
    }
    float sn = dinv[node];
    sn *= sn;
    float2 xv = bfpair(*reinterpret_cast<const unsigned int*>(&xb[(size_t)node * FIN + lane * 2]));
    ushort2 o = {f2bf_rn(ax + xv.x * sn), f2bf_rn(ay + xv.y * sn)};
    *reinterpret_cast<ushort2*>(&z[(size_t)node * FIN + lane * 2]) = o;
}

// ---------------- MFMA bf16 GEMM: h1t[col][row] = bf16(gelu(A@Bt^T + bias)) ----------------
// Output TRANSPOSED [256][NP]: acc r=0..3 are 4 consecutive rows -> packed 8 B stores.

__global__ __launch_bounds__(256)
void gemm_mfma_kernel(const bhalf* __restrict__ A, const bhalf* __restrict__ Bt,
                      const float* __restrict__ bias, bhalf* __restrict__ h1t,
                      int M, int Kp) {
    __shared__ bhalf As[128 * 72];   // rows x (64+8 pad): 144 B row stride (16B-aligned)
    __shared__ bhalf Bs[128 * 72];
    const int tid  = threadIdx.x;
    const int lane = tid & 63;
    const int wave = tid >> 6;
    const int quad = lane >> 4;
    const int l15  = lane & 15;
    const int wm = (wave & 1) * 64;
    const int wn = (wave >> 1) * 64;
    const int bm = blockIdx.x * 128;
    const int bn = blockIdx.y * 128;

    f32x4 acc[4][4] = {};

    for (int k0 = 0; k0 < Kp; k0 += 64) {
#pragma unroll
        for (int i = 0; i < 4; i++) {
            int chunk = tid + i * 256;           // 1024 chunks of 8 bf16
            int r = chunk >> 3, c16 = chunk & 7;
            int gm = bm + r;
            float4 va = make_float4(0.f, 0.f, 0.f, 0.f);
            if (gm < M) va = *reinterpret_cast<const float4*>(&A[(size_t)gm * Kp + k0 + c16 * 8]);
            *reinterpret_cast<float4*>(&As[r * 72 + c16 * 8]) = va;
            float4 vb = *reinterpret_cast<const float4*>(&Bt[(size_t)(bn + r) * Kp + k0 + c16 * 8]);
            *reinterpret_cast<float4*>(&Bs[r * 72 + c16 * 8]) = vb;
        }
        __syncthreads();
#pragma unroll
        for (int kk = 0; kk < 64; kk += 32) {
            bf16x8 af[4], bfr[4];
#pragma unroll
            for (int mi = 0; mi < 4; mi++)
                af[mi] = *reinterpret_cast<const bf16x8*>(&As[(wm + mi * 16 + l15) * 72 + kk + quad * 8]);
#pragma unroll
            for (int ni = 0; ni < 4; ni++)
                bfr[ni] = *reinterpret_cast<const bf16x8*>(&Bs[(wn + ni * 16 + l15) * 72 + kk + quad * 8]);
#pragma unroll
            for (int mi = 0; mi < 4; mi++)
#pragma unroll
                for (int ni = 0; ni < 4; ni++)
                    acc[mi][ni] = __builtin_amdgcn_mfma_f32_16x16x32_bf16(af[mi], bfr[ni], acc[mi][ni], 0, 0, 0);
        }
        __syncthreads();
    }

    // epilogue: C/D col = lane&15, row = quad*4 + r. Write transposed: h1t[col][row0..row0+3].
#pragma unroll
    for (int mi = 0; mi < 4; mi++) {
        int row0 = bm + wm + mi * 16 + quad * 4;   // rows row0..row0+3 < NP always
#pragma unroll
        for (int ni = 0; ni < 4; ni++) {
            int col = bn + wn + ni * 16 + l15;
            float bv = bias[col];
            u16x4 o;
#pragma unroll
            for (int r = 0; r < 4; r++) {
                float v = acc[mi][ni][r] + bv;
                v = 0.5f * v * (1.0f + erff(v * 0.70710678118654752f));
                o[r] = f2bf_rn(v);
            }
            *reinterpret_cast<u16x4*>(&h1t[(size_t)col * NP + row0]) = o;
        }
    }
}

// ---------------- qsum MFMA: qT[256][64] partials = h1t @ {wthi,wtlo}^T over K chunk ----------------
// Both operands K(=node)-contiguous; garbage h1t tail killed by zero wt tail.

__global__ __launch_bounds__(256)
void qsum_mfma_kernel(const bhalf* __restrict__ h1t, const bhalf* __restrict__ wthi,
                      const bhalf* __restrict__ wtlo, float* __restrict__ qpart) {
    const int tid  = threadIdx.x;
    const int lane = tid & 63;
    const int wave = tid >> 6;
    const int quad = lane >> 4;
    const int l15  = lane & 15;
    const int m0 = wave * 64;
    const size_t kbase = (size_t)blockIdx.x * 256 + quad * 8;
    f32x4 acc[4][4] = {};
#pragma unroll
    for (int ks = 0; ks < 8; ks++) {
        size_t k0 = kbase + ks * 32;
        bf16x8 af[4], bh[4], bl[4];
#pragma unroll
        for (int mi = 0; mi < 4; mi++)
            af[mi] = *reinterpret_cast<const bf16x8*>(&h1t[(size_t)(m0 + mi * 16 + l15) * NP + k0]);
#pragma unroll
        for (int ni = 0; ni < 4; ni++) {
            bh[ni] = *reinterpret_cast<const bf16x8*>(&wthi[(size_t)(ni * 16 + l15) * NP + k0]);
            bl[ni] = *reinterpret_cast<const bf16x8*>(&wtlo[(size_t)(ni * 16 + l15) * NP + k0]);
        }
#pragma unroll
        for (int mi = 0; mi < 4; mi++)
#pragma unroll
            for (int ni = 0; ni < 4; ni++) {
                acc[mi][ni] = __builtin_amdgcn_mfma_f32_16x16x32_bf16(af[mi], bh[ni], acc[mi][ni], 0, 0, 0);
                acc[mi][ni] = __builtin_amdgcn_mfma_f32_16x16x32_bf16(af[mi], bl[ni], acc[mi][ni], 0, 0, 0);
            }
    }
    float* qp = &qpart[(size_t)blockIdx.x * FH * NG];
#pragma unroll
    for (int mi = 0; mi < 4; mi++)
#pragma unroll
        for (int r = 0; r < 4; r++) {
            int row = m0 + mi * 16 + quad * 4 + r;   // c-dim 0..255
#pragma unroll
            for (int ni = 0; ni < 4; ni++) {
                int col = ni * 16 + l15;             // g-dim 0..63
                qp[row * NG + col] = acc[mi][ni][r];
            }
        }
}

__global__ __launch_bounds__(256)
void qreduce_kernel(const float* __restrict__ qpart, float* __restrict__ q) {
    int idx = blockIdx.x * 256 + threadIdx.x;   // 16384 cells of qT [c][g]
    float s = 0.0f;
    for (int b = 0; b < QSK; b++)
        s += qpart[(size_t)b * FH * NG + idx];
    q[idx] = s;
}

// ---------------- pooled = (qT^T @ W2) / cnt_g + b2 ----------------

__global__ __launch_bounds__(256)
void p2_kernel(const float* __restrict__ q, const float* __restrict__ W2,
               const float* __restrict__ b2, const int* __restrict__ batch,
               float* __restrict__ pooled) {
    int g = blockIdx.x;
    int c = threadIdx.x;
    int lo = 0, hi = NNODES;
    while (lo < hi) { int m = (lo + hi) >> 1; if (batch[m] < g) lo = m + 1; else hi = m; }
    int a = lo;
    lo = 0; hi = NNODES;
    while (lo < hi) { int m = (lo + hi) >> 1; if (batch[m] < g + 1) lo = m + 1; else hi = m; }
    float inv = 1.0f / fmaxf((float)(lo - a), 1.0f);
    float acc = 0.0f;
    for (int k = 0; k < FH; k++)
        acc += q[k * NG + g] * W2[k * FH + c];   // qT[k][g]
    pooled[g * FH + c] = acc * inv + b2[c];
}

// ---------------- FC head ----------------

__global__ __launch_bounds__(64)
void fc_kernel(const float* __restrict__ pooled, const float* __restrict__ Wfc,
               const float* __restrict__ bfc, float* __restrict__ out) {
    int g = blockIdx.x;
    int c2 = threadIdx.x;
    float acc = 0.0f;
    for (int c = 0; c < FH; c++)
        acc += pooled[g * FH + c] * Wfc[c * NC + c2];
    out[g * NC + c2] = acc + bfc[c2];
}

// ---------------- launch ----------------

extern "C" void kernel_launch(void* const* d_in, const int* in_sizes, int n_in,
                              void* d_out, int out_size, void* d_ws, size_t ws_size,
                              hipStream_t stream) {
    const float* x    = (const float*)d_in[0];
    const int*   ei   = (const int*)d_in[1];
    const int*   batch= (const int*)d_in[2];
    const float* W1   = (const float*)d_in[3];
    const float* b1   = (const float*)d_in[4];
    const float* W2   = (const float*)d_in[5];
    const float* b2   = (const float*)d_in[6];
    const float* Wfc  = (const float*)d_in[7];
    const float* bfc  = (const float*)d_in[8];
    float* out = (float*)d_out;

    const int* src = ei;
    const int* dst = ei + NEDGES;

    // workspace (~94 MB):
    bhalf* xb        = (bhalf*)d_ws;                       // [N,128] bf16 (12.8 MB)
    bhalf* zb        = xb + (size_t)NNODES * FIN;          // [N,128] bf16 (12.8 MB)
    bhalf* h1t       = zb + (size_t)NNODES * FIN;          // [256,NP] bf16 (25.7 MB)
    unsigned int* edata = (unsigned int*)(h1t + (size_t)FH * NP);  // [E] packed (3.2 MB)
    int*   row_start = (int*)(edata + NEDGES);             // [N]
    int*   local_ex  = row_start + NNODES;                 // [N]
    int*   partial   = local_ex + NNODES;                  // [256]
    float* dinv      = (float*)(partial + 256);            // [N]
    bhalf* w1t       = (bhalf*)(dinv + NNODES);            // [256,128] bf16
    bhalf* wthi      = w1t + 256 * FIN;                    // [64,NP] bf16 (6.4 MB)
    bhalf* wtlo      = wthi + (size_t)NG * NP;             // [64,NP] bf16 (6.4 MB)
    float* qpart     = (float*)(wtlo + (size_t)NG * NP);   // [QSK,256,64] f32 (12.85 MB)
    float* q         = qpart + (size_t)QSK * FH * NG;      // [256,64] qT
    float* pooled    = q + FH * NG;                        // [64,256]
    // ---- contiguous zeroed region ----
    int*   degi      = (int*)(pooled + NG * FH);           // [N]
    int*   cursor    = degi + NNODES;                      // [N]
    float* wt        = (float*)(cursor + NNODES);          // [64,NP] f32 (12.85 MB, zero tail!)
    size_t zero_bytes = (size_t)(2 * NNODES) * 4 + (size_t)NG * NP * 4;

    (void)hipMemsetAsync(degi, 0, zero_bytes, stream);

    // ---- CSR build + norms + pooling weights (merged) ----
    degree_kernel<<<(NEDGES + 255) / 256, 256, 0, stream>>>(dst, degi, NEDGES);
    scan_block_kernel<<<SCAN_NB, 256, 0, stream>>>(degi, local_ex, partial, dinv, NNODES);
    scan_partial_kernel<<<1, 256, 0, stream>>>(partial, SCAN_NB);
    add_offsets_kernel<<<SCAN_NB, 256, 0, stream>>>(row_start, local_ex, partial,
                                                    batch, dinv, wt, NNODES);
    edge_place_kernel<<<(NEDGES + 255) / 256, 256, 0, stream>>>(src, dst, row_start, cursor,
                                                                dinv, batch, edata, wt, NEDGES);
    cvt_wt_kernel<<<(NG * NP / 4 + 255) / 256, 256, 0, stream>>>(wt, wthi, wtlo, NG * NP / 4);

    // ---- bf16 conversions ----
    split_x_kernel<<<(NNODES * FIN / 4 + 255) / 256, 256, 0, stream>>>(x, xb, NNODES * FIN / 4);
    split_w_kernel<<<(FIN * 256 + 255) / 256, 256, 0, stream>>>(W1, w1t, FIN);

    int gather_blocks = (NNODES + 3) / 4;
    dim3 mgrid((NNODES + 127) / 128, 2);

    // conv1 (aggregate-first): z = bf16(Ahat*x) ; h1t = bf16(gelu(z@W1 + b1))^T
    gather128_kernel<<<gather_blocks, 256, 0, stream>>>(xb, edata, row_start, degi,
                                                        dinv, zb, NNODES);
    gemm_mfma_kernel<<<mgrid, 256, 0, stream>>>(zb, w1t, b1, h1t, NNODES, FIN);

    // conv2 + pool collapsed via MFMA: qT = h1t @ wt^T ; pooled = (q@W2)/cnt + b2 ; out = @Wfc
    qsum_mfma_kernel<<<QSK, 256, 0, stream>>>(h1t, wthi, wtlo, qpart);
    qreduce_kernel<<<FH * NG / 256, 256, 0, stream>>>(qpart, q);
    p2_kernel<<<NG, FH, 0, stream>>>(q, W2, b2, batch, pooled);
    fc_kernel<<<NG, NC, 0, stream>>>(pooled, Wfc, bfc, out);
}

// Round 17
// 301.418 us; speedup vs baseline: 1.1378x; 1.1076x over previous
//
#include <hip/hip_runtime.h>
#include <hip/hip_bf16.h>
#include <hip/hip_fp16.h>
#include <math.h>

#define NNODES 50000
#define NEDGES 800000
#define FIN 128
#define FH 256
#define NG 64
#define NC 64
#define SCAN_NB ((NNODES + 255) / 256)
#define NP 50176              // K padded to 196*256
#define QSK 196               // split-K blocks for qsum (NP/256)

typedef unsigned short bhalf;
typedef __attribute__((ext_vector_type(8))) short bf16x8;
typedef __attribute__((ext_vector_type(4))) float f32x4;
typedef __attribute__((ext_vector_type(4))) unsigned short u16x4;

__device__ inline bhalf f2bf_rn(float f) {
    unsigned int u = __float_as_uint(f);
    u += 0x7FFFu + ((u >> 16) & 1u);      // round-to-nearest-even
    return (bhalf)(u >> 16);
}
__device__ inline float bf2f(bhalf h) { return __uint_as_float(((unsigned int)h) << 16); }
__device__ inline float2 bfpair(unsigned int u) {   // [lo16, hi16] -> two floats
    return make_float2(__uint_as_float(u << 16), __uint_as_float(u & 0xFFFF0000u));
}
__device__ inline float edec_norm(unsigned int ed) {  // low 16 bits = f16 norm
    return __half2float(__ushort_as_half((unsigned short)(ed & 0xFFFFu)));
}

// ---------------- degree + per-edge rank (rank = position within dst row) ----------------

__global__ void degree_kernel(const int* __restrict__ dst, int* __restrict__ degi,
                              int* __restrict__ rank, int E) {
    int e = blockIdx.x * blockDim.x + threadIdx.x;
    if (e < E) rank[e] = atomicAdd(&degi[dst[e]], 1);
}

// ---------------- 2-level exclusive scan over degi -> row_start (+ fused dinv) ----------------

__global__ __launch_bounds__(256)
void scan_block_kernel(const int* __restrict__ degi, int* __restrict__ local_ex,
                       int* __restrict__ partial, float* __restrict__ dinv, int Nn) {
    __shared__ int s[256];
    int i = blockIdx.x * 256 + threadIdx.x;
    int v = (i < Nn) ? degi[i] : 0;
    s[threadIdx.x] = v;
    __syncthreads();
#pragma unroll
    for (int off = 1; off < 256; off <<= 1) {
        int t = (threadIdx.x >= off) ? s[threadIdx.x - off] : 0;
        __syncthreads();
        s[threadIdx.x] += t;
        __syncthreads();
    }
    if (i < Nn) {
        local_ex[i] = s[threadIdx.x] - v;
        dinv[i] = rsqrtf((float)v + 1.0f);
    }
    if (threadIdx.x == 255) partial[blockIdx.x] = s[255];
}

__global__ __launch_bounds__(256)
void scan_partial_kernel(int* __restrict__ partial, int nb) {
    __shared__ int s[256];
    int v = (threadIdx.x < nb) ? partial[threadIdx.x] : 0;
    s[threadIdx.x] = v;
    __syncthreads();
#pragma unroll
    for (int off = 1; off < 256; off <<= 1) {
        int t = (threadIdx.x >= off) ? s[threadIdx.x - off] : 0;
        __syncthreads();
        s[threadIdx.x] += t;
        __syncthreads();
    }
    if (threadIdx.x < nb) partial[threadIdx.x] = s[threadIdx.x] - v;
}

// ---------------- add offsets + wt self-loop term ----------------

__global__ void add_offsets_kernel(int* __restrict__ row_start, const int* __restrict__ local_ex,
                                   const int* __restrict__ partial, const int* __restrict__ batch,
                                   const float* __restrict__ dinv, float* __restrict__ wt, int Nn) {
    int i = blockIdx.x * 256 + threadIdx.x;
    if (i < Nn) {
        row_start[i] = local_ex[i] + partial[blockIdx.x];
        float sn = dinv[i];
        atomicAdd(&wt[(size_t)batch[i] * NP + i], sn * sn);
    }
}

// ---------------- edge placement + pooling-weight build (merged, NO cursor atomics) ----------------
// pos = row_start[d] + rank[e]; also wt[batch[d]][s] += norm.

__global__ void edge_place_kernel(const int* __restrict__ src, const int* __restrict__ dst,
                                  const int* __restrict__ row_start, const int* __restrict__ rank,
                                  const float* __restrict__ dinv, const int* __restrict__ batch,
                                  unsigned int* __restrict__ edata, float* __restrict__ wt, int E) {
    int e = blockIdx.x * blockDim.x + threadIdx.x;
    if (e >= E) return;
    int s = src[e], d = dst[e];
    int pos = row_start[d] + rank[e];
    float nm = dinv[s] * dinv[d];
    unsigned short hb = __half_as_ushort(__float2half(nm));
    edata[pos] = ((unsigned int)s << 16) | (unsigned int)hb;
    atomicAdd(&wt[(size_t)batch[d] * NP + s], nm);
}

// ---------------- wt f32 -> bf16 hi/lo split (error-free to ~2^-16) ----------------

__global__ void cvt_wt_kernel(const float* __restrict__ wt, bhalf* __restrict__ wthi,
                              bhalf* __restrict__ wtlo, int total4) {
    int i = blockIdx.x * blockDim.x + threadIdx.x;
    if (i >= total4) return;
    float4 v = *reinterpret_cast<const float4*>(&wt[i * 4]);
    u16x4 hi = {f2bf_rn(v.x), f2bf_rn(v.y), f2bf_rn(v.z), f2bf_rn(v.w)};
    u16x4 lo = {f2bf_rn(v.x - bf2f(hi.x)), f2bf_rn(v.y - bf2f(hi.y)),
                f2bf_rn(v.z - bf2f(hi.z)), f2bf_rn(v.w - bf2f(hi.w))};
    *reinterpret_cast<u16x4*>(&wthi[i * 4]) = hi;
    *reinterpret_cast<u16x4*>(&wtlo[i * 4]) = lo;
}

// ---------------- x -> bf16 copy ----------------

__global__ void split_x_kernel(const float* __restrict__ x, bhalf* __restrict__ xb, int total4) {
    int i = blockIdx.x * blockDim.x + threadIdx.x;
    if (i >= total4) return;
    float4 v = *reinterpret_cast<const float4*>(&x[i * 4]);
    u16x4 o = {f2bf_rn(v.x), f2bf_rn(v.y), f2bf_rn(v.z), f2bf_rn(v.w)};
    *reinterpret_cast<u16x4*>(&xb[i * 4]) = o;
}

// ---------------- weight round+transpose: W1[K][256] f32 -> Wt [256][K] bf16 ----------------

__global__ void split_w_kernel(const float* __restrict__ W, bhalf* __restrict__ Wt, int K) {
    int idx = blockIdx.x * 256 + threadIdx.x;
    if (idx >= K * 256) return;
    int k = idx >> 8, n = idx & 255;
    Wt[n * K + k] = f2bf_rn(W[idx]);
}

// ---------------- CSR gather, 128 bf16 feats: z[n] = bf16(sum + x[n]*sn), unroll-4 ----------------

__global__ __launch_bounds__(256)
void gather128_kernel(const bhalf* __restrict__ xb, const unsigned int* __restrict__ edata,
                      const int* __restrict__ row_start, const int* __restrict__ degi,
                      const float* __restrict__ dinv, bhalf* __restrict__ z, int Nn) {
    int node = blockIdx.x * 4 + (threadIdx.x >> 6);
    if (node >= Nn) return;
    int lane = threadIdx.x & 63;
    int st = row_start[node];
    int cnt = degi[node];
    float ax = 0.0f, ay = 0.0f;
    int j = 0;
    for (; j + 3 < cnt; j += 4) {
        unsigned int e0 = edata[st + j],     e1 = edata[st + j + 1];
        unsigned int e2 = edata[st + j + 2], e3 = edata[st + j + 3];
        float2 v0 = bfpair(*reinterpret_cast<const unsigned int*>(&xb[(size_t)(e0 >> 16) * FIN + lane * 2]));
        float2 v1 = bfpair(*reinterpret_cast<const unsigned int*>(&xb[(size_t)(e1 >> 16) * FIN + lane * 2]));
        float2 v2 = bfpair(*reinterpret_cast<const unsigned int*>(&xb[(size_t)(e2 >> 16) * FIN + lane * 2]));
        float2 v3 = bfpair(*reinterpret_cast<const unsigned int*>(&xb[(size_t)(e3 >> 16) * FIN + lane * 2]));
        float n0 = edec_norm(e0), n1 = edec_norm(e1), n2 = edec_norm(e2), n3 = edec_norm(e3);
        ax += v0.x * n0 + v1.x * n1 + v2.x * n2 + v3.x * n3;
        ay += v0.y * n0 + v1.y * n1 + v2.y * n2 + v3.y * n3;
    }
    for (; j < cnt; j++) {
        unsigned int e0 = edata[st + j];
        float2 v0 = bfpair(*reinterpret_cast<const unsigned int*>(&xb[(size_t)(e0 >> 16) * FIN + lane * 2]));
        float n0 = edec_norm(e0);
        ax += v0.x * n0; ay += v0.y * n0;
    }
    float sn = dinv[node];
    sn *= sn;
    float2 xv = bfpair(*reinterpret_cast<const unsigned int*>(&xb[(size_t)node * FIN + lane * 2]));
    ushort2 o = {f2bf_rn(ax + xv.x * sn), f2bf_rn(ay + xv.y * sn)};
    *reinterpret_cast<ushort2*>(&z[(size_t)node * FIN + lane * 2]) = o;
}

// ---------------- MFMA bf16 GEMM: h1t[col][row] = bf16(gelu(A@Bt^T + bias)) ----------------
// Output TRANSPOSED [256][NP]: acc r=0..3 are 4 consecutive rows -> packed 8 B stores.

__global__ __launch_bounds__(256)
void gemm_mfma_kernel(const bhalf* __restrict__ A, const bhalf* __restrict__ Bt,
                      const float* __restrict__ bias, bhalf* __restrict__ h1t,
                      int M, int Kp) {
    __shared__ bhalf As[128 * 72];   // rows x (64+8 pad): 144 B row stride (16B-aligned)
    __shared__ bhalf Bs[128 * 72];
    const int tid  = threadIdx.x;
    const int lane = tid & 63;
    const int wave = tid >> 6;
    const int quad = lane >> 4;
    const int l15  = lane & 15;
    const int wm = (wave & 1) * 64;
    const int wn = (wave >> 1) * 64;
    const int bm = blockIdx.x * 128;
    const int bn = blockIdx.y * 128;

    f32x4 acc[4][4] = {};

    for (int k0 = 0; k0 < Kp; k0 += 64) {
#pragma unroll
        for (int i = 0; i < 4; i++) {
            int chunk = tid + i * 256;           // 1024 chunks of 8 bf16
            int r = chunk >> 3, c16 = chunk & 7;
            int gm = bm + r;
            float4 va = make_float4(0.f, 0.f, 0.f, 0.f);
            if (gm < M) va = *reinterpret_cast<const float4*>(&A[(size_t)gm * Kp + k0 + c16 * 8]);
            *reinterpret_cast<float4*>(&As[r * 72 + c16 * 8]) = va;
            float4 vb = *reinterpret_cast<const float4*>(&Bt[(size_t)(bn + r) * Kp + k0 + c16 * 8]);
            *reinterpret_cast<float4*>(&Bs[r * 72 + c16 * 8]) = vb;
        }
        __syncthreads();
#pragma unroll
        for (int kk = 0; kk < 64; kk += 32) {
            bf16x8 af[4], bfr[4];
#pragma unroll
            for (int mi = 0; mi < 4; mi++)
                af[mi] = *reinterpret_cast<const bf16x8*>(&As[(wm + mi * 16 + l15) * 72 + kk + quad * 8]);
#pragma unroll
            for (int ni = 0; ni < 4; ni++)
                bfr[ni] = *reinterpret_cast<const bf16x8*>(&Bs[(wn + ni * 16 + l15) * 72 + kk + quad * 8]);
#pragma unroll
            for (int mi = 0; mi < 4; mi++)
#pragma unroll
                for (int ni = 0; ni < 4; ni++)
                    acc[mi][ni] = __builtin_amdgcn_mfma_f32_16x16x32_bf16(af[mi], bfr[ni], acc[mi][ni], 0, 0, 0);
        }
        __syncthreads();
    }

    // epilogue: C/D col = lane&15, row = quad*4 + r. Write transposed: h1t[col][row0..row0+3].
#pragma unroll
    for (int mi = 0; mi < 4; mi++) {
        int row0 = bm + wm + mi * 16 + quad * 4;   // rows row0..row0+3 < NP always
#pragma unroll
        for (int ni = 0; ni < 4; ni++) {
            int col = bn + wn + ni * 16 + l15;
            float bv = bias[col];
            u16x4 o;
#pragma unroll
            for (int r = 0; r < 4; r++) {
                float v = acc[mi][ni][r] + bv;
                v = 0.5f * v * (1.0f + erff(v * 0.70710678118654752f));
                o[r] = f2bf_rn(v);
            }
            *reinterpret_cast<u16x4*>(&h1t[(size_t)col * NP + row0]) = o;
        }
    }
}

// ---------------- qsum MFMA: qT[256][64] partials = h1t @ {wthi,wtlo}^T over K chunk ----------------
// Both operands K(=node)-contiguous; garbage h1t tail killed by zero wt tail.

__global__ __launch_bounds__(256)
void qsum_mfma_kernel(const bhalf* __restrict__ h1t, const bhalf* __restrict__ wthi,
                      const bhalf* __restrict__ wtlo, float* __restrict__ qpart) {
    const int tid  = threadIdx.x;
    const int lane = tid & 63;
    const int wave = tid >> 6;
    const int quad = lane >> 4;
    const int l15  = lane & 15;
    const int m0 = wave * 64;
    const size_t kbase = (size_t)blockIdx.x * 256 + quad * 8;
    f32x4 acc[4][4] = {};
#pragma unroll
    for (int ks = 0; ks < 8; ks++) {
        size_t k0 = kbase + ks * 32;
        bf16x8 af[4], bh[4], bl[4];
#pragma unroll
        for (int mi = 0; mi < 4; mi++)
            af[mi] = *reinterpret_cast<const bf16x8*>(&h1t[(size_t)(m0 + mi * 16 + l15) * NP + k0]);
#pragma unroll
        for (int ni = 0; ni < 4; ni++) {
            bh[ni] = *reinterpret_cast<const bf16x8*>(&wthi[(size_t)(ni * 16 + l15) * NP + k0]);
            bl[ni] = *reinterpret_cast<const bf16x8*>(&wtlo[(size_t)(ni * 16 + l15) * NP + k0]);
        }
#pragma unroll
        for (int mi = 0; mi < 4; mi++)
#pragma unroll
            for (int ni = 0; ni < 4; ni++) {
                acc[mi][ni] = __builtin_amdgcn_mfma_f32_16x16x32_bf16(af[mi], bh[ni], acc[mi][ni], 0, 0, 0);
                acc[mi][ni] = __builtin_amdgcn_mfma_f32_16x16x32_bf16(af[mi], bl[ni], acc[mi][ni], 0, 0, 0);
            }
    }
    float* qp = &qpart[(size_t)blockIdx.x * FH * NG];
#pragma unroll
    for (int mi = 0; mi < 4; mi++)
#pragma unroll
        for (int r = 0; r < 4; r++) {
            int row = m0 + mi * 16 + quad * 4 + r;   // c-dim 0..255
#pragma unroll
            for (int ni = 0; ni < 4; ni++) {
                int col = ni * 16 + l15;             // g-dim 0..63
                qp[row * NG + col] = acc[mi][ni][r];
            }
        }
}

__global__ __launch_bounds__(256)
void qreduce_kernel(const float* __restrict__ qpart, float* __restrict__ q) {
    int idx = blockIdx.x * 256 + threadIdx.x;   // 16384 cells of qT [c][g]
    float s = 0.0f;
    for (int b = 0; b < QSK; b++)
        s += qpart[(size_t)b * FH * NG + idx];
    q[idx] = s;
}

// ---------------- pooled = (qT^T @ W2) / cnt_g + b2 ----------------

__global__ __launch_bounds__(256)
void p2_kernel(const float* __restrict__ q, const float* __restrict__ W2,
               const float* __restrict__ b2, const int* __restrict__ batch,
               float* __restrict__ pooled) {
    int g = blockIdx.x;
    int c = threadIdx.x;
    int lo = 0, hi = NNODES;
    while (lo < hi) { int m = (lo + hi) >> 1; if (batch[m] < g) lo = m + 1; else hi = m; }
    int a = lo;
    lo = 0; hi = NNODES;
    while (lo < hi) { int m = (lo + hi) >> 1; if (batch[m] < g + 1) lo = m + 1; else hi = m; }
    float inv = 1.0f / fmaxf((float)(lo - a), 1.0f);
    float acc = 0.0f;
    for (int k = 0; k < FH; k++)
        acc += q[k * NG + g] * W2[k * FH + c];   // qT[k][g]
    pooled[g * FH + c] = acc * inv + b2[c];
}

// ---------------- FC head ----------------

__global__ __launch_bounds__(64)
void fc_kernel(const float* __restrict__ pooled, const float* __restrict__ Wfc,
               const float* __restrict__ bfc, float* __restrict__ out) {
    int g = blockIdx.x;
    int c2 = threadIdx.x;
    float acc = 0.0f;
    for (int c = 0; c < FH; c++)
        acc += pooled[g * FH + c] * Wfc[c * NC + c2];
    out[g * NC + c2] = acc + bfc[c2];
}

// ---------------- launch ----------------

extern "C" void kernel_launch(void* const* d_in, const int* in_sizes, int n_in,
                              void* d_out, int out_size, void* d_ws, size_t ws_size,
                              hipStream_t stream) {
    const float* x    = (const float*)d_in[0];
    const int*   ei   = (const int*)d_in[1];
    const int*   batch= (const int*)d_in[2];
    const float* W1   = (const float*)d_in[3];
    const float* b1   = (const float*)d_in[4];
    const float* W2   = (const float*)d_in[5];
    const float* b2   = (const float*)d_in[6];
    const float* Wfc  = (const float*)d_in[7];
    const float* bfc  = (const float*)d_in[8];
    float* out = (float*)d_out;

    const int* src = ei;
    const int* dst = ei + NEDGES;

    // workspace (~97 MB):
    bhalf* xb        = (bhalf*)d_ws;                       // [N,128] bf16 (12.8 MB)
    bhalf* zb        = xb + (size_t)NNODES * FIN;          // [N,128] bf16 (12.8 MB)
    bhalf* h1t       = zb + (size_t)NNODES * FIN;          // [256,NP] bf16 (25.7 MB)
    unsigned int* edata = (unsigned int*)(h1t + (size_t)FH * NP);  // [E] packed (3.2 MB)
    int*   rank      = (int*)(edata + NEDGES);             // [E] (3.2 MB)
    int*   row_start = rank + NEDGES;                      // [N]
    int*   local_ex  = row_start + NNODES;                 // [N]
    int*   partial   = local_ex + NNODES;                  // [256]
    float* dinv      = (float*)(partial + 256);            // [N]
    bhalf* w1t       = (bhalf*)(dinv + NNODES);            // [256,128] bf16
    bhalf* wthi      = w1t + 256 * FIN;                    // [64,NP] bf16 (6.4 MB)
    bhalf* wtlo      = wthi + (size_t)NG * NP;             // [64,NP] bf16 (6.4 MB)
    float* qpart     = (float*)(wtlo + (size_t)NG * NP);   // [QSK,256,64] f32 (12.85 MB)
    float* q         = qpart + (size_t)QSK * FH * NG;      // [256,64] qT
    float* pooled    = q + FH * NG;                        // [64,256]
    // ---- contiguous zeroed region ----
    int*   degi      = (int*)(pooled + NG * FH);           // [N]
    float* wt        = (float*)(degi + NNODES);            // [64,NP] f32 (12.85 MB, zero tail!)
    size_t zero_bytes = (size_t)NNODES * 4 + (size_t)NG * NP * 4;

    (void)hipMemsetAsync(degi, 0, zero_bytes, stream);

    // ---- CSR build + norms + pooling weights (rank-based, no cursor atomics) ----
    degree_kernel<<<(NEDGES + 255) / 256, 256, 0, stream>>>(dst, degi, rank, NEDGES);
    scan_block_kernel<<<SCAN_NB, 256, 0, stream>>>(degi, local_ex, partial, dinv, NNODES);
    scan_partial_kernel<<<1, 256, 0, stream>>>(partial, SCAN_NB);
    add_offsets_kernel<<<SCAN_NB, 256, 0, stream>>>(row_start, local_ex, partial,
                                                    batch, dinv, wt, NNODES);
    edge_place_kernel<<<(NEDGES + 255) / 256, 256, 0, stream>>>(src, dst, row_start, rank,
                                                                dinv, batch, edata, wt, NEDGES);
    cvt_wt_kernel<<<(NG * NP / 4 + 255) / 256, 256, 0, stream>>>(wt, wthi, wtlo, NG * NP / 4);

    // ---- bf16 conversions ----
    split_x_kernel<<<(NNODES * FIN / 4 + 255) / 256, 256, 0, stream>>>(x, xb, NNODES * FIN / 4);
    split_w_kernel<<<(FIN * 256 + 255) / 256, 256, 0, stream>>>(W1, w1t, FIN);

    int gather_blocks = (NNODES + 3) / 4;
    dim3 mgrid((NNODES + 127) / 128, 2);

    // conv1 (aggregate-first): z = bf16(Ahat*x) ; h1t = bf16(gelu(z@W1 + b1))^T
    gather128_kernel<<<gather_blocks, 256, 0, stream>>>(xb, edata, row_start, degi,
                                                        dinv, zb, NNODES);
    gemm_mfma_kernel<<<mgrid, 256, 0, stream>>>(zb, w1t, b1, h1t, NNODES, FIN);

    // conv2 + pool collapsed via MFMA: qT = h1t @ wt^T ; pooled = (q@W2)/cnt + b2 ; out = @Wfc
    qsum_mfma_kernel<<<QSK, 256, 0, stream>>>(h1t, wthi, wtlo, qpart);
    qreduce_kernel<<<FH * NG / 256, 256, 0, stream>>>(qpart, q);
    p2_kernel<<<NG, FH, 0, stream>>>(q, W2, b2, batch, pooled);
    fc_kernel<<<NG, NC, 0, stream>>>(pooled, Wfc, bfc, out);
}

// Round 18
// 290.344 us; speedup vs baseline: 1.1812x; 1.0381x over previous
//
#include <hip/hip_runtime.h>
#include <hip/hip_bf16.h>
#include <hip/hip_fp16.h>
#include <math.h>

#define NNODES 50000
#define NEDGES 800000
#define FIN 128
#define FH 256
#define NG 64
#define NC 64
#define SCAN_NB ((NNODES + 255) / 256)       // 196
#define NP 50176              // K padded to 196*256
#define QSK 196               // split-K blocks for qsum (NP/256)
#define DEG_BLOCKS ((NEDGES + 255) / 256)    // 3125
#define SPLITX_ITEMS (NNODES * FIN / 4)      // 1.6M
#define SPLITX_BLOCKS ((SPLITX_ITEMS + 255) / 256)

typedef unsigned short bhalf;
typedef __attribute__((ext_vector_type(8))) short bf16x8;
typedef __attribute__((ext_vector_type(4))) float f32x4;
typedef __attribute__((ext_vector_type(4))) unsigned short u16x4;

__device__ inline bhalf f2bf_rn(float f) {
    unsigned int u = __float_as_uint(f);
    u += 0x7FFFu + ((u >> 16) & 1u);      // round-to-nearest-even
    return (bhalf)(u >> 16);
}
__device__ inline float bf2f(bhalf h) { return __uint_as_float(((unsigned int)h) << 16); }
__device__ inline float2 bfpair(unsigned int u) {   // [lo16, hi16] -> two floats
    return make_float2(__uint_as_float(u << 16), __uint_as_float(u & 0xFFFF0000u));
}
__device__ inline float edec_norm(unsigned int ed) {  // low 16 bits = f16 norm
    return __half2float(__ushort_as_half((unsigned short)(ed & 0xFFFFu)));
}

// ---------------- degree + per-edge rank, fused with x -> bf16 conversion ----------------
// Blocks [0, DEG_BLOCKS): degree/rank (latency-bound atomics).
// Blocks [DEG_BLOCKS, ...): split_x streaming (fills idle BW).

__global__ void degree_splitx_kernel(const int* __restrict__ dst, int* __restrict__ degi,
                                     int* __restrict__ rank, const float* __restrict__ x,
                                     bhalf* __restrict__ xb) {
    int b = blockIdx.x;
    if (b < DEG_BLOCKS) {
        int e = b * 256 + threadIdx.x;
        if (e < NEDGES) rank[e] = atomicAdd(&degi[dst[e]], 1);
    } else {
        int i = (b - DEG_BLOCKS) * 256 + threadIdx.x;
        if (i < SPLITX_ITEMS) {
            float4 v = *reinterpret_cast<const float4*>(&x[i * 4]);
            u16x4 o = {f2bf_rn(v.x), f2bf_rn(v.y), f2bf_rn(v.z), f2bf_rn(v.w)};
            *reinterpret_cast<u16x4*>(&xb[i * 4]) = o;
        }
    }
}

// ---------------- block-scan over degi (per-block sums to partial) + fused dinv ----------------

__global__ __launch_bounds__(256)
void scan_block_kernel(const int* __restrict__ degi, int* __restrict__ local_ex,
                       int* __restrict__ partial, float* __restrict__ dinv, int Nn) {
    __shared__ int s[256];
    int i = blockIdx.x * 256 + threadIdx.x;
    int v = (i < Nn) ? degi[i] : 0;
    s[threadIdx.x] = v;
    __syncthreads();
#pragma unroll
    for (int off = 1; off < 256; off <<= 1) {
        int t = (threadIdx.x >= off) ? s[threadIdx.x - off] : 0;
        __syncthreads();
        s[threadIdx.x] += t;
        __syncthreads();
    }
    if (i < Nn) {
        local_ex[i] = s[threadIdx.x] - v;
        dinv[i] = rsqrtf((float)v + 1.0f);
    }
    if (threadIdx.x == 255) partial[blockIdx.x] = s[255];   // raw block sum
}

// ---------------- add offsets (computes own block prefix) + wt self-loop + split_w ----------------

__global__ __launch_bounds__(256)
void add_offsets_kernel(int* __restrict__ row_start, const int* __restrict__ local_ex,
                        const int* __restrict__ partial, const int* __restrict__ batch,
                        const float* __restrict__ dinv, float* __restrict__ wt,
                        const float* __restrict__ W1, bhalf* __restrict__ w1t, int Nn) {
    __shared__ int s[256];
    int t = threadIdx.x;
    s[t] = (t < blockIdx.x) ? partial[t] : 0;   // SCAN_NB (196) <= 256
    __syncthreads();
#pragma unroll
    for (int off = 128; off > 0; off >>= 1) {
        if (t < off) s[t] += s[t + off];
        __syncthreads();
    }
    int prefix = s[0];
    int i = blockIdx.x * 256 + t;
    if (i < Nn) {
        row_start[i] = local_ex[i] + prefix;
        float sn = dinv[i];
        atomicAdd(&wt[(size_t)batch[i] * NP + i], sn * sn);
    }
    if (i < FIN * 256) {                        // fused split_w: W1[K][256] -> w1t[256][K]
        int k = i >> 8, n = i & 255;
        w1t[n * FIN + k] = f2bf_rn(W1[i]);
    }
}

// ---------------- edge placement + pooling-weight build (merged, rank-based) ----------------

__global__ void edge_place_kernel(const int* __restrict__ src, const int* __restrict__ dst,
                                  const int* __restrict__ row_start, const int* __restrict__ rank,
                                  const float* __restrict__ dinv, const int* __restrict__ batch,
                                  unsigned int* __restrict__ edata, float* __restrict__ wt, int E) {
    int e = blockIdx.x * blockDim.x + threadIdx.x;
    if (e >= E) return;
    int s = src[e], d = dst[e];
    int pos = row_start[d] + rank[e];
    float nm = dinv[s] * dinv[d];
    unsigned short hb = __half_as_ushort(__float2half(nm));
    edata[pos] = ((unsigned int)s << 16) | (unsigned int)hb;
    atomicAdd(&wt[(size_t)batch[d] * NP + s], nm);
}

// ---------------- wt f32 -> bf16 hi/lo split (error-free to ~2^-16) ----------------

__global__ void cvt_wt_kernel(const float* __restrict__ wt, bhalf* __restrict__ wthi,
                              bhalf* __restrict__ wtlo, int total4) {
    int i = blockIdx.x * blockDim.x + threadIdx.x;
    if (i >= total4) return;
    float4 v = *reinterpret_cast<const float4*>(&wt[i * 4]);
    u16x4 hi = {f2bf_rn(v.x), f2bf_rn(v.y), f2bf_rn(v.z), f2bf_rn(v.w)};
    u16x4 lo = {f2bf_rn(v.x - bf2f(hi.x)), f2bf_rn(v.y - bf2f(hi.y)),
                f2bf_rn(v.z - bf2f(hi.z)), f2bf_rn(v.w - bf2f(hi.w))};
    *reinterpret_cast<u16x4*>(&wthi[i * 4]) = hi;
    *reinterpret_cast<u16x4*>(&wtlo[i * 4]) = lo;
}

// ---------------- CSR gather, 128 bf16 feats: z[n] = bf16(sum + x[n]*sn), unroll-4 ----------------

__global__ __launch_bounds__(256)
void gather128_kernel(const bhalf* __restrict__ xb, const unsigned int* __restrict__ edata,
                      const int* __restrict__ row_start, const int* __restrict__ degi,
                      const float* __restrict__ dinv, bhalf* __restrict__ z, int Nn) {
    int node = blockIdx.x * 4 + (threadIdx.x >> 6);
    if (node >= Nn) return;
    int lane = threadIdx.x & 63;
    int st = row_start[node];
    int cnt = degi[node];
    float ax = 0.0f, ay = 0.0f;
    int j = 0;
    for (; j + 3 < cnt; j += 4) {
        unsigned int e0 = edata[st + j],     e1 = edata[st + j + 1];
        unsigned int e2 = edata[st + j + 2], e3 = edata[st + j + 3];
        float2 v0 = bfpair(*reinterpret_cast<const unsigned int*>(&xb[(size_t)(e0 >> 16) * FIN + lane * 2]));
        float2 v1 = bfpair(*reinterpret_cast<const unsigned int*>(&xb[(size_t)(e1 >> 16) * FIN + lane * 2]));
        float2 v2 = bfpair(*reinterpret_cast<const unsigned int*>(&xb[(size_t)(e2 >> 16) * FIN + lane * 2]));
        float2 v3 = bfpair(*reinterpret_cast<const unsigned int*>(&xb[(size_t)(e3 >> 16) * FIN + lane * 2]));
        float n0 = edec_norm(e0), n1 = edec_norm(e1), n2 = edec_norm(e2), n3 = edec_norm(e3);
        ax += v0.x * n0 + v1.x * n1 + v2.x * n2 + v3.x * n3;
        ay += v0.y * n0 + v1.y * n1 + v2.y * n2 + v3.y * n3;
    }
    for (; j < cnt; j++) {
        unsigned int e0 = edata[st + j];
        float2 v0 = bfpair(*reinterpret_cast<const unsigned int*>(&xb[(size_t)(e0 >> 16) * FIN + lane * 2]));
        float n0 = edec_norm(e0);
        ax += v0.x * n0; ay += v0.y * n0;
    }
    float sn = dinv[node];
    sn *= sn;
    float2 xv = bfpair(*reinterpret_cast<const unsigned int*>(&xb[(size_t)node * FIN + lane * 2]));
    ushort2 o = {f2bf_rn(ax + xv.x * sn), f2bf_rn(ay + xv.y * sn)};
    *reinterpret_cast<ushort2*>(&z[(size_t)node * FIN + lane * 2]) = o;
}

// ---------------- MFMA bf16 GEMM: h1t[col][row] = bf16(gelu(A@Bt^T + bias)) ----------------
// Output TRANSPOSED [256][NP]: acc r=0..3 are 4 consecutive rows -> packed 8 B stores.

__global__ __launch_bounds__(256)
void gemm_mfma_kernel(const bhalf* __restrict__ A, const bhalf* __restrict__ Bt,
                      const float* __restrict__ bias, bhalf* __restrict__ h1t,
                      int M, int Kp) {
    __shared__ bhalf As[128 * 72];   // rows x (64+8 pad): 144 B row stride (16B-aligned)
    __shared__ bhalf Bs[128 * 72];
    const int tid  = threadIdx.x;
    const int lane = tid & 63;
    const int wave = tid >> 6;
    const int quad = lane >> 4;
    const int l15  = lane & 15;
    const int wm = (wave & 1) * 64;
    const int wn = (wave >> 1) * 64;
    const int bm = blockIdx.x * 128;
    const int bn = blockIdx.y * 128;

    f32x4 acc[4][4] = {};

    for (int k0 = 0; k0 < Kp; k0 += 64) {
#pragma unroll
        for (int i = 0; i < 4; i++) {
            int chunk = tid + i * 256;           // 1024 chunks of 8 bf16
            int r = chunk >> 3, c16 = chunk & 7;
            int gm = bm + r;
            float4 va = make_float4(0.f, 0.f, 0.f, 0.f);
            if (gm < M) va = *reinterpret_cast<const float4*>(&A[(size_t)gm * Kp + k0 + c16 * 8]);
            *reinterpret_cast<float4*>(&As[r * 72 + c16 * 8]) = va;
            float4 vb = *reinterpret_cast<const float4*>(&Bt[(size_t)(bn + r) * Kp + k0 + c16 * 8]);
            *reinterpret_cast<float4*>(&Bs[r * 72 + c16 * 8]) = vb;
        }
        __syncthreads();
#pragma unroll
        for (int kk = 0; kk < 64; kk += 32) {
            bf16x8 af[4], bfr[4];
#pragma unroll
            for (int mi = 0; mi < 4; mi++)
                af[mi] = *reinterpret_cast<const bf16x8*>(&As[(wm + mi * 16 + l15) * 72 + kk + quad * 8]);
#pragma unroll
            for (int ni = 0; ni < 4; ni++)
                bfr[ni] = *reinterpret_cast<const bf16x8*>(&Bs[(wn + ni * 16 + l15) * 72 + kk + quad * 8]);
#pragma unroll
            for (int mi = 0; mi < 4; mi++)
#pragma unroll
                for (int ni = 0; ni < 4; ni++)
                    acc[mi][ni] = __builtin_amdgcn_mfma_f32_16x16x32_bf16(af[mi], bfr[ni], acc[mi][ni], 0, 0, 0);
        }
        __syncthreads();
    }

    // epilogue: C/D col = lane&15, row = quad*4 + r. Write transposed: h1t[col][row0..row0+3].
#pragma unroll
    for (int mi = 0; mi < 4; mi++) {
        int row0 = bm + wm + mi * 16 + quad * 4;   // rows row0..row0+3 < NP always
#pragma unroll
        for (int ni = 0; ni < 4; ni++) {
            int col = bn + wn + ni * 16 + l15;
            float bv = bias[col];
            u16x4 o;
#pragma unroll
            for (int r = 0; r < 4; r++) {
                float v = acc[mi][ni][r] + bv;
                v = 0.5f * v * (1.0f + erff(v * 0.70710678118654752f));
                o[r] = f2bf_rn(v);
            }
            *reinterpret_cast<u16x4*>(&h1t[(size_t)col * NP + row0]) = o;
        }
    }
}

// ---------------- qsum MFMA: qT[256][64] partials = h1t @ {wthi,wtlo}^T over K chunk ----------------

__global__ __launch_bounds__(256)
void qsum_mfma_kernel(const bhalf* __restrict__ h1t, const bhalf* __restrict__ wthi,
                      const bhalf* __restrict__ wtlo, float* __restrict__ qpart) {
    const int tid  = threadIdx.x;
    const int lane = tid & 63;
    const int wave = tid >> 6;
    const int quad = lane >> 4;
    const int l15  = lane & 15;
    const int m0 = wave * 64;
    const size_t kbase = (size_t)blockIdx.x * 256 + quad * 8;
    f32x4 acc[4][4] = {};
#pragma unroll
    for (int ks = 0; ks < 8; ks++) {
        size_t k0 = kbase + ks * 32;
        bf16x8 af[4], bh[4], bl[4];
#pragma unroll
        for (int mi = 0; mi < 4; mi++)
            af[mi] = *reinterpret_cast<const bf16x8*>(&h1t[(size_t)(m0 + mi * 16 + l15) * NP + k0]);
#pragma unroll
        for (int ni = 0; ni < 4; ni++) {
            bh[ni] = *reinterpret_cast<const bf16x8*>(&wthi[(size_t)(ni * 16 + l15) * NP + k0]);
            bl[ni] = *reinterpret_cast<const bf16x8*>(&wtlo[(size_t)(ni * 16 + l15) * NP + k0]);
        }
#pragma unroll
        for (int mi = 0; mi < 4; mi++)
#pragma unroll
            for (int ni = 0; ni < 4; ni++) {
                acc[mi][ni] = __builtin_amdgcn_mfma_f32_16x16x32_bf16(af[mi], bh[ni], acc[mi][ni], 0, 0, 0);
                acc[mi][ni] = __builtin_amdgcn_mfma_f32_16x16x32_bf16(af[mi], bl[ni], acc[mi][ni], 0, 0, 0);
            }
    }
    float* qp = &qpart[(size_t)blockIdx.x * FH * NG];
#pragma unroll
    for (int mi = 0; mi < 4; mi++)
#pragma unroll
        for (int r = 0; r < 4; r++) {
            int row = m0 + mi * 16 + quad * 4 + r;   // c-dim 0..255
#pragma unroll
            for (int ni = 0; ni < 4; ni++) {
                int col = ni * 16 + l15;             // g-dim 0..63
                qp[row * NG + col] = acc[mi][ni][r];
            }
        }
}

__global__ __launch_bounds__(256)
void qreduce_kernel(const float* __restrict__ qpart, float* __restrict__ q) {
    int idx = blockIdx.x * 256 + threadIdx.x;   // 16384 cells of qT [c][g]
    float s = 0.0f;
    for (int b = 0; b < QSK; b++)
        s += qpart[(size_t)b * FH * NG + idx];
    q[idx] = s;
}

// ---------------- fused head: pooled (LDS) = (qT^T@W2)/cnt + b2 ; out = pooled@Wfc + bfc ----------------

__global__ __launch_bounds__(256)
void p2fc_kernel(const float* __restrict__ q, const float* __restrict__ W2,
                 const float* __restrict__ b2, const int* __restrict__ batch,
                 const float* __restrict__ Wfc, const float* __restrict__ bfc,
                 float* __restrict__ out) {
    __shared__ float ps[FH];
    int g = blockIdx.x;
    int c = threadIdx.x;
    int lo = 0, hi = NNODES;
    while (lo < hi) { int m = (lo + hi) >> 1; if (batch[m] < g) lo = m + 1; else hi = m; }
    int a = lo;
    lo = 0; hi = NNODES;
    while (lo < hi) { int m = (lo + hi) >> 1; if (batch[m] < g + 1) lo = m + 1; else hi = m; }
    float inv = 1.0f / fmaxf((float)(lo - a), 1.0f);
    float acc = 0.0f;
    for (int k = 0; k < FH; k++)
        acc += q[k * NG + g] * W2[k * FH + c];   // qT[k][g]
    ps[c] = acc * inv + b2[c];
    __syncthreads();
    if (c < NC) {
        float a2 = 0.0f;
        for (int cc = 0; cc < FH; cc++)
            a2 += ps[cc] * Wfc[cc * NC + c];
        out[g * NC + c] = a2 + bfc[c];
    }
}

// ---------------- launch ----------------

extern "C" void kernel_launch(void* const* d_in, const int* in_sizes, int n_in,
                              void* d_out, int out_size, void* d_ws, size_t ws_size,
                              hipStream_t stream) {
    const float* x    = (const float*)d_in[0];
    const int*   ei   = (const int*)d_in[1];
    const int*   batch= (const int*)d_in[2];
    const float* W1   = (const float*)d_in[3];
    const float* b1   = (const float*)d_in[4];
    const float* W2   = (const float*)d_in[5];
    const float* b2   = (const float*)d_in[6];
    const float* Wfc  = (const float*)d_in[7];
    const float* bfc  = (const float*)d_in[8];
    float* out = (float*)d_out;

    const int* src = ei;
    const int* dst = ei + NEDGES;

    // workspace (~97 MB):
    bhalf* xb        = (bhalf*)d_ws;                       // [N,128] bf16 (12.8 MB)
    bhalf* zb        = xb + (size_t)NNODES * FIN;          // [N,128] bf16 (12.8 MB)
    bhalf* h1t       = zb + (size_t)NNODES * FIN;          // [256,NP] bf16 (25.7 MB)
    unsigned int* edata = (unsigned int*)(h1t + (size_t)FH * NP);  // [E] packed (3.2 MB)
    int*   rank      = (int*)(edata + NEDGES);             // [E] (3.2 MB)
    int*   row_start = rank + NEDGES;                      // [N]
    int*   local_ex  = row_start + NNODES;                 // [N]
    int*   partial   = local_ex + NNODES;                  // [256]
    float* dinv      = (float*)(partial + 256);            // [N]
    bhalf* w1t       = (bhalf*)(dinv + NNODES);            // [256,128] bf16
    bhalf* wthi      = w1t + 256 * FIN;                    // [64,NP] bf16 (6.4 MB)
    bhalf* wtlo      = wthi + (size_t)NG * NP;             // [64,NP] bf16 (6.4 MB)
    float* qpart     = (float*)(wtlo + (size_t)NG * NP);   // [QSK,256,64] f32 (12.85 MB)
    float* q         = qpart + (size_t)QSK * FH * NG;      // [256,64] qT
    // ---- contiguous zeroed region ----
    int*   degi      = (int*)(q + FH * NG);                // [N]
    float* wt        = (float*)(degi + NNODES);            // [64,NP] f32 (12.85 MB, zero tail!)
    size_t zero_bytes = (size_t)NNODES * 4 + (size_t)NG * NP * 4;

    (void)hipMemsetAsync(degi, 0, zero_bytes, stream);

    // ---- CSR build + norms + pooling weights (fused pipeline, 5 dispatches) ----
    degree_splitx_kernel<<<DEG_BLOCKS + SPLITX_BLOCKS, 256, 0, stream>>>(dst, degi, rank, x, xb);
    scan_block_kernel<<<SCAN_NB, 256, 0, stream>>>(degi, local_ex, partial, dinv, NNODES);
    add_offsets_kernel<<<SCAN_NB, 256, 0, stream>>>(row_start, local_ex, partial,
                                                    batch, dinv, wt, W1, w1t, NNODES);
    edge_place_kernel<<<(NEDGES + 255) / 256, 256, 0, stream>>>(src, dst, row_start, rank,
                                                                dinv, batch, edata, wt, NEDGES);
    cvt_wt_kernel<<<(NG * NP / 4 + 255) / 256, 256, 0, stream>>>(wt, wthi, wtlo, NG * NP / 4);

    int gather_blocks = (NNODES + 3) / 4;
    dim3 mgrid((NNODES + 127) / 128, 2);

    // conv1 (aggregate-first): z = bf16(Ahat*x) ; h1t = bf16(gelu(z@W1 + b1))^T
    gather128_kernel<<<gather_blocks, 256, 0, stream>>>(xb, edata, row_start, degi,
                                                        dinv, zb, NNODES);
    gemm_mfma_kernel<<<mgrid, 256, 0, stream>>>(zb, w1t, b1, h1t, NNODES, FIN);

    // conv2 + pool collapsed via MFMA: qT = h1t @ wt^T ; out = ((q@W2)/cnt + b2)@Wfc + bfc
    qsum_mfma_kernel<<<QSK, 256, 0, stream>>>(h1t, wthi, wtlo, qpart);
    qreduce_kernel<<<FH * NG / 256, 256, 0, stream>>>(qpart, q);
    p2fc_kernel<<<NG, FH, 0, stream>>>(q, W2, b2, batch, Wfc, bfc, out);
}

// Round 19
// 277.950 us; speedup vs baseline: 1.2338x; 1.0446x over previous
//
#include <hip/hip_runtime.h>
#include <hip/hip_bf16.h>
#include <hip/hip_fp16.h>
#include <math.h>

#define NNODES 50000
#define NEDGES 800000
#define FIN 128
#define FH 256
#define NG 64
#define NC 64
#define SCAN_NB ((NNODES + 255) / 256)       // 196
#define NP 50176              // K padded to 196*256
#define QSK 196               // split-K blocks for qsum (NP/256)
#define DEG_BLOCKS ((NEDGES + 255) / 256)    // 3125
#define SPLITX_ITEMS (NNODES * FIN / 4)      // 1.6M
#define SPLITX_BLOCKS ((SPLITX_ITEMS + 255) / 256)   // 6250
#define WTZ_ITEMS (NG * NP / 4)              // 802816
#define WTZ_BLOCKS ((WTZ_ITEMS + 255) / 256)         // 3136
#define GEMM_MB ((NNODES + 127) / 128)       // 391
#define GEMM_BLKS (GEMM_MB * 2)              // 782
#define CVT_ITEMS (NG * NP / 4)
#define CVT_BLOCKS ((CVT_ITEMS + 255) / 256) // 3136

typedef unsigned short bhalf;
typedef __attribute__((ext_vector_type(8))) short bf16x8;
typedef __attribute__((ext_vector_type(4))) float f32x4;
typedef __attribute__((ext_vector_type(4))) unsigned short u16x4;

__device__ inline bhalf f2bf_rn(float f) {
    unsigned int u = __float_as_uint(f);
    u += 0x7FFFu + ((u >> 16) & 1u);      // round-to-nearest-even
    return (bhalf)(u >> 16);
}
__device__ inline float bf2f(bhalf h) { return __uint_as_float(((unsigned int)h) << 16); }
__device__ inline float2 bfpair(unsigned int u) {   // [lo16, hi16] -> two floats
    return make_float2(__uint_as_float(u << 16), __uint_as_float(u & 0xFFFF0000u));
}
__device__ inline float edec_norm(unsigned int ed) {  // low 16 bits = f16 norm
    return __half2float(__ushort_as_half((unsigned short)(ed & 0xFFFFu)));
}

// ---------------- degree/rank + x->bf16 + wt zeroing (3 block ranges) ----------------
// wt is first written 2 dispatches later (add_offsets) -> zeroing here is safe.

__global__ void degree_splitx_kernel(const int* __restrict__ dst, int* __restrict__ degi,
                                     int* __restrict__ rank, const float* __restrict__ x,
                                     bhalf* __restrict__ xb, float* __restrict__ wt) {
    int b = blockIdx.x;
    if (b < DEG_BLOCKS) {
        int e = b * 256 + threadIdx.x;
        if (e < NEDGES) rank[e] = atomicAdd(&degi[dst[e]], 1);
    } else if (b < DEG_BLOCKS + SPLITX_BLOCKS) {
        int i = (b - DEG_BLOCKS) * 256 + threadIdx.x;
        if (i < SPLITX_ITEMS) {
            float4 v = *reinterpret_cast<const float4*>(&x[i * 4]);
            u16x4 o = {f2bf_rn(v.x), f2bf_rn(v.y), f2bf_rn(v.z), f2bf_rn(v.w)};
            *reinterpret_cast<u16x4*>(&xb[i * 4]) = o;
        }
    } else {
        int i = (b - DEG_BLOCKS - SPLITX_BLOCKS) * 256 + threadIdx.x;
        if (i < WTZ_ITEMS) {
            f32x4 zr = {0.f, 0.f, 0.f, 0.f};
            *reinterpret_cast<f32x4*>(&wt[i * 4]) = zr;
        }
    }
}

// ---------------- block-scan over degi (per-block sums to partial) + fused dinv ----------------

__global__ __launch_bounds__(256)
void scan_block_kernel(const int* __restrict__ degi, int* __restrict__ local_ex,
                       int* __restrict__ partial, float* __restrict__ dinv, int Nn) {
    __shared__ int s[256];
    int i = blockIdx.x * 256 + threadIdx.x;
    int v = (i < Nn) ? degi[i] : 0;
    s[threadIdx.x] = v;
    __syncthreads();
#pragma unroll
    for (int off = 1; off < 256; off <<= 1) {
        int t = (threadIdx.x >= off) ? s[threadIdx.x - off] : 0;
        __syncthreads();
        s[threadIdx.x] += t;
        __syncthreads();
    }
    if (i < Nn) {
        local_ex[i] = s[threadIdx.x] - v;
        dinv[i] = rsqrtf((float)v + 1.0f);
    }
    if (threadIdx.x == 255) partial[blockIdx.x] = s[255];   // raw block sum
}

// ---------------- add offsets (computes own block prefix) + wt self-loop + split_w ----------------

__global__ __launch_bounds__(256)
void add_offsets_kernel(int* __restrict__ row_start, const int* __restrict__ local_ex,
                        const int* __restrict__ partial, const int* __restrict__ batch,
                        const float* __restrict__ dinv, float* __restrict__ wt,
                        const float* __restrict__ W1, bhalf* __restrict__ w1t, int Nn) {
    __shared__ int s[256];
    int t = threadIdx.x;
    s[t] = (t < blockIdx.x) ? partial[t] : 0;   // SCAN_NB (196) <= 256
    __syncthreads();
#pragma unroll
    for (int off = 128; off > 0; off >>= 1) {
        if (t < off) s[t] += s[t + off];
        __syncthreads();
    }
    int prefix = s[0];
    int i = blockIdx.x * 256 + t;
    if (i < Nn) {
        row_start[i] = local_ex[i] + prefix;
        float sn = dinv[i];
        atomicAdd(&wt[(size_t)batch[i] * NP + i], sn * sn);
    }
    if (i < FIN * 256) {                        // fused split_w: W1[K][256] -> w1t[256][K]
        int k = i >> 8, n = i & 255;
        w1t[n * FIN + k] = f2bf_rn(W1[i]);
    }
}

// ---------------- edge placement + pooling-weight build (merged, rank-based) ----------------

__global__ void edge_place_kernel(const int* __restrict__ src, const int* __restrict__ dst,
                                  const int* __restrict__ row_start, const int* __restrict__ rank,
                                  const float* __restrict__ dinv, const int* __restrict__ batch,
                                  unsigned int* __restrict__ edata, float* __restrict__ wt, int E) {
    int e = blockIdx.x * blockDim.x + threadIdx.x;
    if (e >= E) return;
    int s = src[e], d = dst[e];
    int pos = row_start[d] + rank[e];
    float nm = dinv[s] * dinv[d];
    unsigned short hb = __half_as_ushort(__float2half(nm));
    edata[pos] = ((unsigned int)s << 16) | (unsigned int)hb;
    atomicAdd(&wt[(size_t)batch[d] * NP + s], nm);
}

// ---------------- CSR gather, 128 bf16 feats: z[n] = bf16(sum + x[n]*sn), unroll-4 ----------------

__global__ __launch_bounds__(256)
void gather128_kernel(const bhalf* __restrict__ xb, const unsigned int* __restrict__ edata,
                      const int* __restrict__ row_start, const int* __restrict__ degi,
                      const float* __restrict__ dinv, bhalf* __restrict__ z, int Nn) {
    int node = blockIdx.x * 4 + (threadIdx.x >> 6);
    if (node >= Nn) return;
    int lane = threadIdx.x & 63;
    int st = row_start[node];
    int cnt = degi[node];
    float ax = 0.0f, ay = 0.0f;
    int j = 0;
    for (; j + 3 < cnt; j += 4) {
        unsigned int e0 = edata[st + j],     e1 = edata[st + j + 1];
        unsigned int e2 = edata[st + j + 2], e3 = edata[st + j + 3];
        float2 v0 = bfpair(*reinterpret_cast<const unsigned int*>(&xb[(size_t)(e0 >> 16) * FIN + lane * 2]));
        float2 v1 = bfpair(*reinterpret_cast<const unsigned int*>(&xb[(size_t)(e1 >> 16) * FIN + lane * 2]));
        float2 v2 = bfpair(*reinterpret_cast<const unsigned int*>(&xb[(size_t)(e2 >> 16) * FIN + lane * 2]));
        float2 v3 = bfpair(*reinterpret_cast<const unsigned int*>(&xb[(size_t)(e3 >> 16) * FIN + lane * 2]));
        float n0 = edec_norm(e0), n1 = edec_norm(e1), n2 = edec_norm(e2), n3 = edec_norm(e3);
        ax += v0.x * n0 + v1.x * n1 + v2.x * n2 + v3.x * n3;
        ay += v0.y * n0 + v1.y * n1 + v2.y * n2 + v3.y * n3;
    }
    for (; j < cnt; j++) {
        unsigned int e0 = edata[st + j];
        float2 v0 = bfpair(*reinterpret_cast<const unsigned int*>(&xb[(size_t)(e0 >> 16) * FIN + lane * 2]));
        float n0 = edec_norm(e0);
        ax += v0.x * n0; ay += v0.y * n0;
    }
    float sn = dinv[node];
    sn *= sn;
    float2 xv = bfpair(*reinterpret_cast<const unsigned int*>(&xb[(size_t)node * FIN + lane * 2]));
    ushort2 o = {f2bf_rn(ax + xv.x * sn), f2bf_rn(ay + xv.y * sn)};
    *reinterpret_cast<ushort2*>(&z[(size_t)node * FIN + lane * 2]) = o;
}

// ---------------- MFMA bf16 GEMM (transposed out) + fused cvt_wt (block ranges) ----------------
// Blocks [0, GEMM_BLKS): h1t = bf16(gelu(zb@w1t^T + b1))^T.
// Blocks [GEMM_BLKS, ...): wt f32 -> wthi/wtlo bf16 split (independent streaming).

__global__ __launch_bounds__(256)
void gemm_cvt_kernel(const bhalf* __restrict__ A, const bhalf* __restrict__ Bt,
                     const float* __restrict__ bias, bhalf* __restrict__ h1t,
                     const float* __restrict__ wt, bhalf* __restrict__ wthi,
                     bhalf* __restrict__ wtlo, int M, int Kp) {
    __shared__ bhalf As[128 * 72];   // rows x (64+8 pad): 144 B row stride
    __shared__ bhalf Bs[128 * 72];
    if (blockIdx.x >= GEMM_BLKS) {
        int i = (blockIdx.x - GEMM_BLKS) * 256 + threadIdx.x;
        if (i < CVT_ITEMS) {
            float4 v = *reinterpret_cast<const float4*>(&wt[i * 4]);
            u16x4 hi = {f2bf_rn(v.x), f2bf_rn(v.y), f2bf_rn(v.z), f2bf_rn(v.w)};
            u16x4 lo = {f2bf_rn(v.x - bf2f(hi.x)), f2bf_rn(v.y - bf2f(hi.y)),
                        f2bf_rn(v.z - bf2f(hi.z)), f2bf_rn(v.w - bf2f(hi.w))};
            *reinterpret_cast<u16x4*>(&wthi[i * 4]) = hi;
            *reinterpret_cast<u16x4*>(&wtlo[i * 4]) = lo;
        }
        return;
    }
    const int tid  = threadIdx.x;
    const int lane = tid & 63;
    const int wave = tid >> 6;
    const int quad = lane >> 4;
    const int l15  = lane & 15;
    const int wm = (wave & 1) * 64;
    const int wn = (wave >> 1) * 64;
    const int bm = (blockIdx.x >> 1) * 128;
    const int bn = (blockIdx.x & 1) * 128;

    f32x4 acc[4][4] = {};

    for (int k0 = 0; k0 < Kp; k0 += 64) {
#pragma unroll
        for (int i = 0; i < 4; i++) {
            int chunk = tid + i * 256;           // 1024 chunks of 8 bf16
            int r = chunk >> 3, c16 = chunk & 7;
            int gm = bm + r;
            float4 va = make_float4(0.f, 0.f, 0.f, 0.f);
            if (gm < M) va = *reinterpret_cast<const float4*>(&A[(size_t)gm * Kp + k0 + c16 * 8]);
            *reinterpret_cast<float4*>(&As[r * 72 + c16 * 8]) = va;
            float4 vb = *reinterpret_cast<const float4*>(&Bt[(size_t)(bn + r) * Kp + k0 + c16 * 8]);
            *reinterpret_cast<float4*>(&Bs[r * 72 + c16 * 8]) = vb;
        }
        __syncthreads();
#pragma unroll
        for (int kk = 0; kk < 64; kk += 32) {
            bf16x8 af[4], bfr[4];
#pragma unroll
            for (int mi = 0; mi < 4; mi++)
                af[mi] = *reinterpret_cast<const bf16x8*>(&As[(wm + mi * 16 + l15) * 72 + kk + quad * 8]);
#pragma unroll
            for (int ni = 0; ni < 4; ni++)
                bfr[ni] = *reinterpret_cast<const bf16x8*>(&Bs[(wn + ni * 16 + l15) * 72 + kk + quad * 8]);
#pragma unroll
            for (int mi = 0; mi < 4; mi++)
#pragma unroll
                for (int ni = 0; ni < 4; ni++)
                    acc[mi][ni] = __builtin_amdgcn_mfma_f32_16x16x32_bf16(af[mi], bfr[ni], acc[mi][ni], 0, 0, 0);
        }
        __syncthreads();
    }

    // epilogue: C/D col = lane&15, row = quad*4 + r. Write transposed: h1t[col][row0..row0+3].
#pragma unroll
    for (int mi = 0; mi < 4; mi++) {
        int row0 = bm + wm + mi * 16 + quad * 4;
#pragma unroll
        for (int ni = 0; ni < 4; ni++) {
            int col = bn + wn + ni * 16 + l15;
            float bv = bias[col];
            u16x4 o;
#pragma unroll
            for (int r = 0; r < 4; r++) {
                float v = acc[mi][ni][r] + bv;
                v = 0.5f * v * (1.0f + erff(v * 0.70710678118654752f));
                o[r] = f2bf_rn(v);
            }
            *reinterpret_cast<u16x4*>(&h1t[(size_t)col * NP + row0]) = o;
        }
    }
}

// ---------------- qsum MFMA: qpart[b][g][k] = h1t @ {wthi,wtlo}^T over K chunk ----------------
// [g][k] layout: f32x4 stores (r=0..3 consecutive k), coalesced p2fc reads.

__global__ __launch_bounds__(256)
void qsum_mfma_kernel(const bhalf* __restrict__ h1t, const bhalf* __restrict__ wthi,
                      const bhalf* __restrict__ wtlo, float* __restrict__ qpart) {
    const int tid  = threadIdx.x;
    const int lane = tid & 63;
    const int wave = tid >> 6;
    const int quad = lane >> 4;
    const int l15  = lane & 15;
    const int m0 = wave * 64;
    const size_t kbase = (size_t)blockIdx.x * 256 + quad * 8;
    f32x4 acc[4][4] = {};
#pragma unroll
    for (int ks = 0; ks < 8; ks++) {
        size_t k0 = kbase + ks * 32;
        bf16x8 af[4], bh[4], bl[4];
#pragma unroll
        for (int mi = 0; mi < 4; mi++)
            af[mi] = *reinterpret_cast<const bf16x8*>(&h1t[(size_t)(m0 + mi * 16 + l15) * NP + k0]);
#pragma unroll
        for (int ni = 0; ni < 4; ni++) {
            bh[ni] = *reinterpret_cast<const bf16x8*>(&wthi[(size_t)(ni * 16 + l15) * NP + k0]);
            bl[ni] = *reinterpret_cast<const bf16x8*>(&wtlo[(size_t)(ni * 16 + l15) * NP + k0]);
        }
#pragma unroll
        for (int mi = 0; mi < 4; mi++)
#pragma unroll
            for (int ni = 0; ni < 4; ni++) {
                acc[mi][ni] = __builtin_amdgcn_mfma_f32_16x16x32_bf16(af[mi], bh[ni], acc[mi][ni], 0, 0, 0);
                acc[mi][ni] = __builtin_amdgcn_mfma_f32_16x16x32_bf16(af[mi], bl[ni], acc[mi][ni], 0, 0, 0);
            }
    }
    float* qp = &qpart[(size_t)blockIdx.x * NG * FH];
#pragma unroll
    for (int mi = 0; mi < 4; mi++) {
        int row0 = m0 + mi * 16 + quad * 4;          // k-dim 0..255 (4 consecutive)
#pragma unroll
        for (int ni = 0; ni < 4; ni++) {
            int col = ni * 16 + l15;                 // g-dim 0..63
            f32x4 o = {acc[mi][ni][0], acc[mi][ni][1], acc[mi][ni][2], acc[mi][ni][3]};
            *reinterpret_cast<f32x4*>(&qp[(size_t)col * FH + row0]) = o;
        }
    }
}

// ---------------- fused head: q-reduce + pooled = (q@W2)/cnt + b2 ; out = pooled@Wfc + bfc ----------------

__global__ __launch_bounds__(256)
void p2fc_kernel(const float* __restrict__ qpart, const float* __restrict__ W2,
                 const float* __restrict__ b2, const int* __restrict__ batch,
                 const float* __restrict__ Wfc, const float* __restrict__ bfc,
                 float* __restrict__ out) {
    __shared__ float qg[FH];
    __shared__ float ps[FH];
    int g = blockIdx.x;
    int t = threadIdx.x;
    float s = 0.0f;
    for (int b = 0; b < QSK; b++)                    // coalesced: consecutive t -> consecutive k
        s += qpart[(size_t)b * NG * FH + (size_t)g * FH + t];
    qg[t] = s;
    int lo = 0, hi = NNODES;
    while (lo < hi) { int m = (lo + hi) >> 1; if (batch[m] < g) lo = m + 1; else hi = m; }
    int a = lo;
    lo = 0; hi = NNODES;
    while (lo < hi) { int m = (lo + hi) >> 1; if (batch[m] < g + 1) lo = m + 1; else hi = m; }
    float inv = 1.0f / fmaxf((float)(lo - a), 1.0f);
    __syncthreads();
    float acc = 0.0f;
    for (int k = 0; k < FH; k++)
        acc += qg[k] * W2[k * FH + t];
    ps[t] = acc * inv + b2[t];
    __syncthreads();
    if (t < NC) {
        float a2 = 0.0f;
        for (int cc = 0; cc < FH; cc++)
            a2 += ps[cc] * Wfc[cc * NC + t];
        out[g * NC + t] = a2 + bfc[t];
    }
}

// ---------------- launch ----------------

extern "C" void kernel_launch(void* const* d_in, const int* in_sizes, int n_in,
                              void* d_out, int out_size, void* d_ws, size_t ws_size,
                              hipStream_t stream) {
    const float* x    = (const float*)d_in[0];
    const int*   ei   = (const int*)d_in[1];
    const int*   batch= (const int*)d_in[2];
    const float* W1   = (const float*)d_in[3];
    const float* b1   = (const float*)d_in[4];
    const float* W2   = (const float*)d_in[5];
    const float* b2   = (const float*)d_in[6];
    const float* Wfc  = (const float*)d_in[7];
    const float* bfc  = (const float*)d_in[8];
    float* out = (float*)d_out;

    const int* src = ei;
    const int* dst = ei + NEDGES;

    // workspace (~97 MB):
    bhalf* xb        = (bhalf*)d_ws;                       // [N,128] bf16 (12.8 MB)
    bhalf* zb        = xb + (size_t)NNODES * FIN;          // [N,128] bf16 (12.8 MB)
    bhalf* h1t       = zb + (size_t)NNODES * FIN;          // [256,NP] bf16 (25.7 MB)
    unsigned int* edata = (unsigned int*)(h1t + (size_t)FH * NP);  // [E] packed (3.2 MB)
    int*   rank      = (int*)(edata + NEDGES);             // [E] (3.2 MB)
    int*   row_start = rank + NEDGES;                      // [N]
    int*   local_ex  = row_start + NNODES;                 // [N]
    int*   partial   = local_ex + NNODES;                  // [256]
    float* dinv      = (float*)(partial + 256);            // [N]
    bhalf* w1t       = (bhalf*)(dinv + NNODES);            // [256,128] bf16
    bhalf* wthi      = w1t + 256 * FIN;                    // [64,NP] bf16 (6.4 MB)
    bhalf* wtlo      = wthi + (size_t)NG * NP;             // [64,NP] bf16 (6.4 MB)
    float* qpart     = (float*)(wtlo + (size_t)NG * NP);   // [QSK,64,256] f32, [g][k] (12.85 MB)
    float* wt        = qpart + (size_t)QSK * NG * FH;      // [64,NP] f32 (zeroed in-kernel)
    int*   degi      = (int*)(wt + (size_t)NG * NP);       // [N] (memset)

    (void)hipMemsetAsync(degi, 0, (size_t)NNODES * 4, stream);

    // ---- CSR build + norms + pooling weights ----
    degree_splitx_kernel<<<DEG_BLOCKS + SPLITX_BLOCKS + WTZ_BLOCKS, 256, 0, stream>>>(
        dst, degi, rank, x, xb, wt);
    scan_block_kernel<<<SCAN_NB, 256, 0, stream>>>(degi, local_ex, partial, dinv, NNODES);
    add_offsets_kernel<<<SCAN_NB, 256, 0, stream>>>(row_start, local_ex, partial,
                                                    batch, dinv, wt, W1, w1t, NNODES);
    edge_place_kernel<<<(NEDGES + 255) / 256, 256, 0, stream>>>(src, dst, row_start, rank,
                                                                dinv, batch, edata, wt, NEDGES);

    // conv1 (aggregate-first): z = bf16(Ahat*x) ; h1t = bf16(gelu(z@W1 + b1))^T ; cvt_wt fused
    gather128_kernel<<<(NNODES + 3) / 4, 256, 0, stream>>>(xb, edata, row_start, degi,
                                                           dinv, zb, NNODES);
    gemm_cvt_kernel<<<GEMM_BLKS + CVT_BLOCKS, 256, 0, stream>>>(zb, w1t, b1, h1t,
                                                                wt, wthi, wtlo, NNODES, FIN);

    // conv2 + pool collapsed via MFMA: qT = h1t @ wt^T ; out = ((q@W2)/cnt + b2)@Wfc + bfc
    qsum_mfma_kernel<<<QSK, 256, 0, stream>>>(h1t, wthi, wtlo, qpart);
    p2fc_kernel<<<NG, FH, 0, stream>>>(qpart, W2, b2, batch, Wfc, bfc, out);
}